// Round 6
// baseline (672.792 us; speedup 1.0000x reference)
//
#include <hip/hip_runtime.h>
#include <cfloat>
#include <cstdint>
#include <cstddef>

#define N_NODES 100000
#define N_EDGES 1600000
#define G_GRAPHS 64
#define SCAN_CHUNK 1024
#define SCAN_BLOCKS ((N_NODES + SCAN_CHUNK - 1) / SCAN_CHUNK)  // 98

// ---------------------------------------------------------------------------
// Dual GEMM: O0 = act(A) @ W0, O1 = act(A) @ W1.  A:[n,K], W:[K,J].
// act = relu(A + bias) when FUSE.  A-tile LDS reads vectorized (b128).
// ---------------------------------------------------------------------------
template <int K, int J, bool FUSE>
__launch_bounds__(256) __global__
void gemm_dual(const float* __restrict__ A, const float* __restrict__ W0,
               const float* __restrict__ W1, const float* __restrict__ bias,
               float* __restrict__ O0, float* __restrict__ O1, int n) {
  constexpr int CPT = J / 32;
  __shared__ __align__(16) float As[32][K];
  __shared__ __align__(16) float Ws[K][J];
  const int tid = threadIdx.x;
  const int n0 = blockIdx.x * 32;

  constexpr int AV = 32 * K / 4;
  for (int i = tid; i < AV; i += 256) {
    const int node = i / (K / 4);
    const int kg = i % (K / 4);
    float4 v = make_float4(0.f, 0.f, 0.f, 0.f);
    if (n0 + node < n) {
      v = reinterpret_cast<const float4*>(A)[(size_t)(n0 + node) * (K / 4) + kg];
      if constexpr (FUSE) {
        const float4 b = reinterpret_cast<const float4*>(bias)[kg];
        v.x = fmaxf(v.x + b.x, 0.f);
        v.y = fmaxf(v.y + b.y, 0.f);
        v.z = fmaxf(v.z + b.z, 0.f);
        v.w = fmaxf(v.w + b.w, 0.f);
      }
    }
    reinterpret_cast<float4*>(&As[node][0])[kg] = v;
  }

  const int tr = tid >> 5;
  const int tc = tid & 31;

  for (int mm = 0; mm < 2; ++mm) {
    const float* __restrict__ W = mm ? W1 : W0;
    float* __restrict__ O = mm ? O1 : O0;
    for (int i = tid; i < K * J / 4; i += 256)
      reinterpret_cast<float4*>(&Ws[0][0])[i] =
          reinterpret_cast<const float4*>(W)[i];
    __syncthreads();

    float acc[4][CPT];
#pragma unroll
    for (int i = 0; i < 4; ++i)
#pragma unroll
      for (int j = 0; j < CPT; ++j) acc[i][j] = 0.f;

#pragma unroll 4
    for (int k4 = 0; k4 < K / 4; ++k4) {
      float a[4][4];
#pragma unroll
      for (int i = 0; i < 4; ++i) {
        const float4 t =
            reinterpret_cast<const float4*>(&As[tr * 4 + i][0])[k4];
        a[i][0] = t.x; a[i][1] = t.y; a[i][2] = t.z; a[i][3] = t.w;
      }
#pragma unroll
      for (int kk = 0; kk < 4; ++kk) {
        const int k = k4 * 4 + kk;
        float w[CPT];
#pragma unroll
        for (int j = 0; j < CPT; ++j) w[j] = Ws[k][tc + 32 * j];
#pragma unroll
        for (int i = 0; i < 4; ++i)
#pragma unroll
          for (int j = 0; j < CPT; ++j)
            acc[i][j] = fmaf(a[i][kk], w[j], acc[i][j]);
      }
    }

#pragma unroll
    for (int i = 0; i < 4; ++i) {
      const int node = n0 + tr * 4 + i;
      if (node < n)
#pragma unroll
        for (int j = 0; j < CPT; ++j)
          O[(size_t)node * J + tc + 32 * j] = acc[i][j];
    }
    __syncthreads();
  }
}

// ---------------------------------------------------------------------------
// CSR build over dst: histogram -> 3-pass multi-block scan -> scatter.
// ---------------------------------------------------------------------------
__launch_bounds__(256) __global__
void hist_kernel(const int* __restrict__ ei, int* __restrict__ deg) {
  const int e = blockIdx.x * 256 + threadIdx.x;
  if (e < N_EDGES) atomicAdd(&deg[ei[N_EDGES + e]], 1);
}

__launch_bounds__(256) __global__
void scan1_kernel(const int* __restrict__ deg, int* __restrict__ bsum) {
  __shared__ int ls[256];
  const int tid = threadIdx.x;
  const int base = blockIdx.x * SCAN_CHUNK + tid * 4;
  int s = 0;
  if (base + 3 < N_NODES) {
    const int4 v = reinterpret_cast<const int4*>(deg)[base >> 2];
    s = v.x + v.y + v.z + v.w;
  } else {
#pragma unroll
    for (int k = 0; k < 4; ++k)
      if (base + k < N_NODES) s += deg[base + k];
  }
  ls[tid] = s;
  __syncthreads();
  for (int d = 128; d > 0; d >>= 1) {
    if (tid < d) ls[tid] += ls[tid + d];
    __syncthreads();
  }
  if (tid == 0) bsum[blockIdx.x] = ls[0];
}

__launch_bounds__(128) __global__
void scan2_kernel(const int* __restrict__ bsum, int* __restrict__ boff) {
  __shared__ int ls[128];
  const int tid = threadIdx.x;
  const int v = (tid < SCAN_BLOCKS) ? bsum[tid] : 0;
  ls[tid] = v;
  __syncthreads();
  for (int d = 1; d < 128; d <<= 1) {
    const int t = (tid >= d) ? ls[tid - d] : 0;
    __syncthreads();
    ls[tid] += t;
    __syncthreads();
  }
  if (tid < SCAN_BLOCKS) boff[tid] = ls[tid] - v;
}

__launch_bounds__(256) __global__
void scan3_kernel(const int* __restrict__ deg, const int* __restrict__ boff,
                  int* __restrict__ row, int* __restrict__ cursor) {
  __shared__ int ls[256];
  const int tid = threadIdx.x;
  const int base = blockIdx.x * SCAN_CHUNK + tid * 4;
  int4 v = make_int4(0, 0, 0, 0);
  if (base + 3 < N_NODES) {
    v = reinterpret_cast<const int4*>(deg)[base >> 2];
  } else {
    if (base + 0 < N_NODES) v.x = deg[base + 0];
    if (base + 1 < N_NODES) v.y = deg[base + 1];
    if (base + 2 < N_NODES) v.z = deg[base + 2];
    if (base + 3 < N_NODES) v.w = deg[base + 3];
  }
  const int s = v.x + v.y + v.z + v.w;
  ls[tid] = s;
  __syncthreads();
  for (int d = 1; d < 256; d <<= 1) {
    const int t = (tid >= d) ? ls[tid - d] : 0;
    __syncthreads();
    ls[tid] += t;
    __syncthreads();
  }
  int run = ls[tid] - s + boff[blockIdx.x];
  const int4 r = make_int4(run, run + v.x, run + v.x + v.y,
                           run + v.x + v.y + v.z);
  if (base + 3 < N_NODES) {
    reinterpret_cast<int4*>(row)[base >> 2] = r;
    reinterpret_cast<int4*>(cursor)[base >> 2] = r;
  } else {
    if (base + 0 < N_NODES) { row[base + 0] = r.x; cursor[base + 0] = r.x; }
    if (base + 1 < N_NODES) { row[base + 1] = r.y; cursor[base + 1] = r.y; }
    if (base + 2 < N_NODES) { row[base + 2] = r.z; cursor[base + 2] = r.z; }
    if (base + 3 < N_NODES) { row[base + 3] = r.w; cursor[base + 3] = r.w; }
  }
}

__launch_bounds__(256) __global__
void scatter_kernel(const int* __restrict__ ei, int* __restrict__ cursor,
                    int* __restrict__ csr_src) {
  const int e = blockIdx.x * 256 + threadIdx.x;
  if (e >= N_EDGES) return;
  const int dst = ei[N_EDGES + e];
  const int pos = atomicAdd(&cursor[dst], 1);
  csr_src[pos] = ei[e];
}

// ---------------------------------------------------------------------------
// Layer 1 fused softmax-aggregate. H=2, C=32. One wave per node.
// No-max softmax; 8-deep software pipeline (8 gathers in flight per wave).
// ---------------------------------------------------------------------------
__launch_bounds__(256) __global__
void gat1_kernel(const float* __restrict__ xl, const float* __restrict__ xr,
                 const float* __restrict__ att, const int* __restrict__ row,
                 const int* __restrict__ deg, const int* __restrict__ csr_src,
                 float* __restrict__ agg) {
  const int n = blockIdx.x * 4 + (threadIdx.x >> 6);
  if (n >= N_NODES) return;
  const int lane = threadIdx.x & 63;
  const int r0 = row[n];
  const int dg = deg[n];

  const float xrv = xr[((size_t)n << 6) + lane];
  const float attv = att[lane];
  const int srcs = (lane < dg) ? csr_src[r0 + lane] : 0;  // lane j = edge j src

  float s = 0.f, acc = 0.f;
  float xb[8];
#pragma unroll
  for (int k = 0; k < 8; ++k) {
    const unsigned sn = (unsigned)__shfl(srcs, k);
    xb[k] = (k < dg) ? xl[((size_t)sn << 6) + lane] : 0.f;
  }
  for (int j = 0; j < dg; j += 8) {
    float xn[8];
#pragma unroll
    for (int k = 0; k < 8; ++k) {
      const int jj = j + 8 + k;
      int sn;
      if (jj < 64) sn = __shfl(srcs, jj & 63);
      else if (jj < dg) sn = csr_src[r0 + jj];
      else sn = 0;
      xn[k] = (jj < dg) ? xl[(((size_t)(unsigned)sn) << 6) + lane] : 0.f;
    }
#pragma unroll
    for (int k = 0; k < 8; ++k) {
      float v = xb[k] + xrv;
      v = fmaxf(v, 0.2f * v);  // leaky_relu
      float p = v * attv;
      p += __shfl_xor(p, 1);
      p += __shfl_xor(p, 2);
      p += __shfl_xor(p, 4);
      p += __shfl_xor(p, 8);
      p += __shfl_xor(p, 16);  // per-head sums
      float e = __expf(p);
      e = (j + k < dg) ? e : 0.f;
      s += e;
      acc = fmaf(e, xb[k], acc);
    }
#pragma unroll
    for (int k = 0; k < 8; ++k) xb[k] = xn[k];
  }
  const float inv = s > 0.f ? 1.f / s : 0.f;
  agg[((size_t)n << 6) + lane] = acc * inv;
}

// ---------------------------------------------------------------------------
// Layer 2 fused: H=1, C=32. Two 32-lane halves, alternating edges, 4-deep
// pipeline per half (8 gathers in flight per wave). No-max softmax.
// Epilogue: bias+relu -> h2, gate scalar inline.
// ---------------------------------------------------------------------------
__launch_bounds__(256) __global__
void gat2_kernel(const float* __restrict__ xl, const float* __restrict__ xr,
                 const float* __restrict__ att, const int* __restrict__ row,
                 const int* __restrict__ deg, const int* __restrict__ csr_src,
                 const float* __restrict__ b2, const float* __restrict__ g1w,
                 const float* __restrict__ g1b, const float* __restrict__ g2w,
                 const float* __restrict__ g2b, float* __restrict__ h2,
                 float* __restrict__ gate) {
  const int n = blockIdx.x * 4 + (threadIdx.x >> 6);
  if (n >= N_NODES) return;
  const int lane = threadIdx.x & 63;
  const int c = lane & 31;
  const int h = lane >> 5;  // half h picks edges h, h+2, h+4, ...
  const int r0 = row[n];
  const int dg = deg[n];

  const float xrv = xr[(size_t)n * 32 + c];
  const float attv = att[c];
  const int srcs = (lane < dg) ? csr_src[r0 + lane] : 0;

  float s = 0.f, acc = 0.f;
  float xb[4];
#pragma unroll
  for (int k = 0; k < 4; ++k) {
    const int jj = h + 2 * k;
    const unsigned sn = (unsigned)__shfl(srcs, jj);
    xb[k] = (jj < dg) ? xl[((size_t)sn << 5) + c] : 0.f;
  }
  for (int j = h; j < dg; j += 8) {
    float xn[4];
#pragma unroll
    for (int k = 0; k < 4; ++k) {
      const int jj = j + 8 + 2 * k;
      int sn;
      if (jj < 64) sn = __shfl(srcs, jj & 63);
      else if (jj < dg) sn = csr_src[r0 + jj];
      else sn = 0;
      xn[k] = (jj < dg) ? xl[(((size_t)(unsigned)sn) << 5) + c] : 0.f;
    }
#pragma unroll
    for (int k = 0; k < 4; ++k) {
      float v = xb[k] + xrv;
      v = fmaxf(v, 0.2f * v);
      float p = v * attv;
      p += __shfl_xor(p, 1);
      p += __shfl_xor(p, 2);
      p += __shfl_xor(p, 4);
      p += __shfl_xor(p, 8);
      p += __shfl_xor(p, 16);  // per-half (per-edge) sum
      float e = __expf(p);
      e = (j + 2 * k < dg) ? e : 0.f;
      s += e;
      acc = fmaf(e, xb[k], acc);
    }
#pragma unroll
    for (int k = 0; k < 4; ++k) xb[k] = xn[k];
  }
  // merge halves
  const float stot = s + __shfl_xor(s, 32);
  const float atot = acc + __shfl_xor(acc, 32);
  const float inv = stot > 0.f ? 1.f / stot : 0.f;
  const float hv = fmaxf(atot * inv + b2[c], 0.f);
  if (h == 0) h2[(size_t)n * 32 + c] = hv;

  // gate = relu(hv @ g1w + g1b) . g2w + g2b (computed redundantly per half)
  float sg = g1b[c];
#pragma unroll
  for (int k = 0; k < 32; ++k)
    sg = fmaf(__shfl(hv, k, 32), g1w[k * 32 + c], sg);
  sg = fmaxf(sg, 0.f);
  float pg = sg * g2w[c];
  pg += __shfl_xor(pg, 1);
  pg += __shfl_xor(pg, 2);
  pg += __shfl_xor(pg, 4);
  pg += __shfl_xor(pg, 8);
  pg += __shfl_xor(pg, 16);
  if (lane == 0) gate[n] = pg + g2b[0];
}

// ---------------------------------------------------------------------------
// ge = exp(gate) (no-max: |gate| small); gd[g] = sum ge; pooled[g][c] = sum
// ge*h2 (division deferred to final_kernel). LDS partials per block.
// ---------------------------------------------------------------------------
__launch_bounds__(256) __global__
void gepool_kernel(const float* __restrict__ h2, const int* __restrict__ batch,
                   const float* __restrict__ gate, float* __restrict__ gd,
                   float* __restrict__ pooled) {
  __shared__ float pool[G_GRAPHS * 32];
  __shared__ float gdb[G_GRAPHS];
  const int tid = threadIdx.x;
  for (int i = tid; i < G_GRAPHS * 32; i += 256) pool[i] = 0.f;
  if (tid < G_GRAPHS) gdb[tid] = 0.f;
  __syncthreads();
  const int c = tid & 31;
  const int hw = tid >> 5;
  const int start = blockIdx.x * 256;
  const int end = min(N_NODES, start + 256);
  for (int n = start + hw; n < end; n += 8) {
    const int b = batch[n];
    const float ge = __expf(gate[n]);
    atomicAdd(&pool[b * 32 + c], ge * h2[(size_t)n * 32 + c]);
    if (c == 0) atomicAdd(&gdb[b], ge);
  }
  __syncthreads();
  for (int i = tid; i < G_GRAPHS * 32; i += 256)
    if (pool[i] != 0.f) unsafeAtomicAdd(&pooled[i], pool[i]);
  if (tid < G_GRAPHS && gdb[tid] != 0.f) unsafeAtomicAdd(&gd[tid], gdb[tid]);
}

__launch_bounds__(64) __global__
void final_kernel(const float* __restrict__ pooled, const float* __restrict__ gd,
                  const float* __restrict__ l1w, const float* __restrict__ l1b,
                  const float* __restrict__ l2w, const float* __restrict__ l2b,
                  float* __restrict__ out) {
  const int g = blockIdx.x;
  const int lane = threadIdx.x;
  if (lane >= 32) return;
  const float invgd = 1.f / gd[g];
  float s = l1b[lane];
#pragma unroll
  for (int k = 0; k < 32; ++k)
    s = fmaf(pooled[g * 32 + k] * invgd, l1w[k * 32 + lane], s);
  s = fmaxf(s, 0.f);
  float p = s * l2w[lane];
  p += __shfl_xor(p, 1);
  p += __shfl_xor(p, 2);
  p += __shfl_xor(p, 4);
  p += __shfl_xor(p, 8);
  p += __shfl_xor(p, 16);
  if (lane == 0) out[g] = p + l2b[0];
}

// ---------------------------------------------------------------------------
extern "C" void kernel_launch(void* const* d_in, const int* in_sizes, int n_in,
                              void* d_out, int out_size, void* d_ws,
                              size_t ws_size, hipStream_t stream) {
  const float* x    = (const float*)d_in[0];
  const int*   ei   = (const int*)d_in[1];
  const int*   batch= (const int*)d_in[2];
  const float* Wl1  = (const float*)d_in[3];
  const float* Wr1  = (const float*)d_in[4];
  const float* att1 = (const float*)d_in[5];
  const float* b1   = (const float*)d_in[6];
  const float* Wl2  = (const float*)d_in[7];
  const float* Wr2  = (const float*)d_in[8];
  const float* att2 = (const float*)d_in[9];
  const float* b2   = (const float*)d_in[10];
  const float* g1w  = (const float*)d_in[11];
  const float* g1b  = (const float*)d_in[12];
  const float* g2w  = (const float*)d_in[13];
  const float* g2b  = (const float*)d_in[14];
  const float* l1w  = (const float*)d_in[15];
  const float* l1b  = (const float*)d_in[16];
  const float* l2w  = (const float*)d_in[17];
  const float* l2b  = (const float*)d_in[18];
  float* out = (float*)d_out;

  // ---- workspace layout ----
  int* deg     = (int*)d_ws;          // N
  int* cursor  = deg + N_NODES;       // N
  int* row     = cursor + N_NODES;    // N
  int* bsum    = row + N_NODES;       // SCAN_BLOCKS
  int* boff    = bsum + SCAN_BLOCKS;  // SCAN_BLOCKS
  int* csr_src = boff + SCAN_BLOCKS;  // E
  float* fbase = (float*)(csr_src + N_EDGES);
  float* xl1  = fbase;                         // N*64
  float* xr1  = xl1 + (size_t)N_NODES * 64;    // N*64
  float* agg1 = xr1 + (size_t)N_NODES * 64;    // N*64
  float* gate = agg1 + (size_t)N_NODES * 64;   // N
  float* gd   = gate + N_NODES;                // 64
  float* pooled = gd + G_GRAPHS;               // 64*32
  // layer-2 aliases (xl1/xr1 dead by the time these are written)
  float* xl2 = xl1;                            // N*32
  float* xr2 = xl1 + (size_t)N_NODES * 32;     // N*32
  float* h2  = xr1;                            // N*32

  hipMemsetAsync(deg, 0, (size_t)N_NODES * sizeof(int), stream);
  hipMemsetAsync(gd, 0, (size_t)(G_GRAPHS + G_GRAPHS * 32) * sizeof(float), stream);

  // CSR build (shared by both layers)
  hist_kernel<<<(N_EDGES + 255) / 256, 256, 0, stream>>>(ei, deg);
  scan1_kernel<<<SCAN_BLOCKS, 256, 0, stream>>>(deg, bsum);
  scan2_kernel<<<1, 128, 0, stream>>>(bsum, boff);
  scan3_kernel<<<SCAN_BLOCKS, 256, 0, stream>>>(deg, boff, row, cursor);
  scatter_kernel<<<(N_EDGES + 255) / 256, 256, 0, stream>>>(ei, cursor, csr_src);

  // Layer 1
  gemm_dual<128, 64, false><<<(N_NODES + 31) / 32, 256, 0, stream>>>(
      x, Wl1, Wr1, nullptr, xl1, xr1, N_NODES);
  gat1_kernel<<<(N_NODES + 3) / 4, 256, 0, stream>>>(xl1, xr1, att1, row, deg,
                                                     csr_src, agg1);

  // Layer 2 (bias1+relu fused into A-load; gate fused into epilogue)
  gemm_dual<64, 32, true><<<(N_NODES + 31) / 32, 256, 0, stream>>>(
      agg1, Wl2, Wr2, b1, xl2, xr2, N_NODES);
  gat2_kernel<<<(N_NODES + 3) / 4, 256, 0, stream>>>(
      xl2, xr2, att2, row, deg, csr_src, b2, g1w, g1b, g2w, g2b, h2, gate);

  // Pooling + head (no-max graph softmax)
  gepool_kernel<<<(N_NODES + 255) / 256, 256, 0, stream>>>(h2, batch, gate, gd,
                                                           pooled);
  final_kernel<<<64, 64, 0, stream>>>(pooled, gd, l1w, l1b, l2w, l2b, out);
}

// Round 7
// 630.060 us; speedup vs baseline: 1.0678x; 1.0678x over previous
//
#include <hip/hip_runtime.h>
#include <cfloat>
#include <cstdint>
#include <cstddef>

#define N_NODES 100000
#define N_EDGES 1600000
#define G_GRAPHS 64
#define SCAN_CHUNK 1024
#define SCAN_BLOCKS ((N_NODES + SCAN_CHUNK - 1) / SCAN_CHUNK)  // 98

// Load a (possibly past-end, padded) csr entry, select 0 if beyond dg, and
// force the result into an SGPR. idx must be within the padded allocation.
__device__ __forceinline__ int ld_src(const int* __restrict__ p, int idx,
                                      int i, int lim) {
  int v = p[idx];
  v = (i < lim) ? v : 0;
  return __builtin_amdgcn_readfirstlane(v);
}

// ---------------------------------------------------------------------------
// Dual GEMM: O0 = act(A) @ W0, O1 = act(A) @ W1.  A:[n,K], W:[K,J].
// act = relu(A + bias) when FUSE.  A-tile LDS reads vectorized (b128).
// ---------------------------------------------------------------------------
template <int K, int J, bool FUSE>
__launch_bounds__(256) __global__
void gemm_dual(const float* __restrict__ A, const float* __restrict__ W0,
               const float* __restrict__ W1, const float* __restrict__ bias,
               float* __restrict__ O0, float* __restrict__ O1, int n) {
  constexpr int CPT = J / 32;
  __shared__ __align__(16) float As[32][K];
  __shared__ __align__(16) float Ws[K][J];
  const int tid = threadIdx.x;
  const int n0 = blockIdx.x * 32;

  constexpr int AV = 32 * K / 4;
  for (int i = tid; i < AV; i += 256) {
    const int node = i / (K / 4);
    const int kg = i % (K / 4);
    float4 v = make_float4(0.f, 0.f, 0.f, 0.f);
    if (n0 + node < n) {
      v = reinterpret_cast<const float4*>(A)[(size_t)(n0 + node) * (K / 4) + kg];
      if constexpr (FUSE) {
        const float4 b = reinterpret_cast<const float4*>(bias)[kg];
        v.x = fmaxf(v.x + b.x, 0.f);
        v.y = fmaxf(v.y + b.y, 0.f);
        v.z = fmaxf(v.z + b.z, 0.f);
        v.w = fmaxf(v.w + b.w, 0.f);
      }
    }
    reinterpret_cast<float4*>(&As[node][0])[kg] = v;
  }

  const int tr = tid >> 5;
  const int tc = tid & 31;

  for (int mm = 0; mm < 2; ++mm) {
    const float* __restrict__ W = mm ? W1 : W0;
    float* __restrict__ O = mm ? O1 : O0;
    for (int i = tid; i < K * J / 4; i += 256)
      reinterpret_cast<float4*>(&Ws[0][0])[i] =
          reinterpret_cast<const float4*>(W)[i];
    __syncthreads();

    float acc[4][CPT];
#pragma unroll
    for (int i = 0; i < 4; ++i)
#pragma unroll
      for (int j = 0; j < CPT; ++j) acc[i][j] = 0.f;

#pragma unroll 4
    for (int k4 = 0; k4 < K / 4; ++k4) {
      float a[4][4];
#pragma unroll
      for (int i = 0; i < 4; ++i) {
        const float4 t =
            reinterpret_cast<const float4*>(&As[tr * 4 + i][0])[k4];
        a[i][0] = t.x; a[i][1] = t.y; a[i][2] = t.z; a[i][3] = t.w;
      }
#pragma unroll
      for (int kk = 0; kk < 4; ++kk) {
        const int k = k4 * 4 + kk;
        float w[CPT];
#pragma unroll
        for (int j = 0; j < CPT; ++j) w[j] = Ws[k][tc + 32 * j];
#pragma unroll
        for (int i = 0; i < 4; ++i)
#pragma unroll
          for (int j = 0; j < CPT; ++j)
            acc[i][j] = fmaf(a[i][kk], w[j], acc[i][j]);
      }
    }

#pragma unroll
    for (int i = 0; i < 4; ++i) {
      const int node = n0 + tr * 4 + i;
      if (node < n)
#pragma unroll
        for (int j = 0; j < CPT; ++j)
          O[(size_t)node * J + tc + 32 * j] = acc[i][j];
    }
    __syncthreads();
  }
}

// ---------------------------------------------------------------------------
// CSR build over dst: histogram -> 3-pass multi-block scan -> scatter.
// ---------------------------------------------------------------------------
__launch_bounds__(256) __global__
void hist_kernel(const int* __restrict__ ei, int* __restrict__ deg) {
  const int e = blockIdx.x * 256 + threadIdx.x;
  if (e < N_EDGES) atomicAdd(&deg[ei[N_EDGES + e]], 1);
}

__launch_bounds__(256) __global__
void scan1_kernel(const int* __restrict__ deg, int* __restrict__ bsum) {
  __shared__ int ls[256];
  const int tid = threadIdx.x;
  const int base = blockIdx.x * SCAN_CHUNK + tid * 4;
  int s = 0;
  if (base + 3 < N_NODES) {
    const int4 v = reinterpret_cast<const int4*>(deg)[base >> 2];
    s = v.x + v.y + v.z + v.w;
  } else {
#pragma unroll
    for (int k = 0; k < 4; ++k)
      if (base + k < N_NODES) s += deg[base + k];
  }
  ls[tid] = s;
  __syncthreads();
  for (int d = 128; d > 0; d >>= 1) {
    if (tid < d) ls[tid] += ls[tid + d];
    __syncthreads();
  }
  if (tid == 0) bsum[blockIdx.x] = ls[0];
}

__launch_bounds__(128) __global__
void scan2_kernel(const int* __restrict__ bsum, int* __restrict__ boff) {
  __shared__ int ls[128];
  const int tid = threadIdx.x;
  const int v = (tid < SCAN_BLOCKS) ? bsum[tid] : 0;
  ls[tid] = v;
  __syncthreads();
  for (int d = 1; d < 128; d <<= 1) {
    const int t = (tid >= d) ? ls[tid - d] : 0;
    __syncthreads();
    ls[tid] += t;
    __syncthreads();
  }
  if (tid < SCAN_BLOCKS) boff[tid] = ls[tid] - v;
}

__launch_bounds__(256) __global__
void scan3_kernel(const int* __restrict__ deg, const int* __restrict__ boff,
                  int* __restrict__ row, int* __restrict__ cursor) {
  __shared__ int ls[256];
  const int tid = threadIdx.x;
  const int base = blockIdx.x * SCAN_CHUNK + tid * 4;
  int4 v = make_int4(0, 0, 0, 0);
  if (base + 3 < N_NODES) {
    v = reinterpret_cast<const int4*>(deg)[base >> 2];
  } else {
    if (base + 0 < N_NODES) v.x = deg[base + 0];
    if (base + 1 < N_NODES) v.y = deg[base + 1];
    if (base + 2 < N_NODES) v.z = deg[base + 2];
    if (base + 3 < N_NODES) v.w = deg[base + 3];
  }
  const int s = v.x + v.y + v.z + v.w;
  ls[tid] = s;
  __syncthreads();
  for (int d = 1; d < 256; d <<= 1) {
    const int t = (tid >= d) ? ls[tid - d] : 0;
    __syncthreads();
    ls[tid] += t;
    __syncthreads();
  }
  int run = ls[tid] - s + boff[blockIdx.x];
  const int4 r = make_int4(run, run + v.x, run + v.x + v.y,
                           run + v.x + v.y + v.z);
  if (base + 3 < N_NODES) {
    reinterpret_cast<int4*>(row)[base >> 2] = r;
    reinterpret_cast<int4*>(cursor)[base >> 2] = r;
  } else {
    if (base + 0 < N_NODES) { row[base + 0] = r.x; cursor[base + 0] = r.x; }
    if (base + 1 < N_NODES) { row[base + 1] = r.y; cursor[base + 1] = r.y; }
    if (base + 2 < N_NODES) { row[base + 2] = r.z; cursor[base + 2] = r.z; }
    if (base + 3 < N_NODES) { row[base + 3] = r.w; cursor[base + 3] = r.w; }
  }
}

__launch_bounds__(256) __global__
void scatter_kernel(const int* __restrict__ ei, int* __restrict__ cursor,
                    int* __restrict__ csr_src) {
  const int e = blockIdx.x * 256 + threadIdx.x;
  if (e >= N_EDGES) return;
  const int dst = ei[N_EDGES + e];
  const int pos = atomicAdd(&cursor[dst], 1);
  csr_src[pos] = ei[e];
}

// ---------------------------------------------------------------------------
// Layer 1 fused softmax-aggregate. H=2, C=32. One wave per node.
// All control state (n, r0, dg, src indices) in SGPRs — no ds_bpermute;
// gather address = SGPR base + lane offset. 8 gathers in flight.
// ---------------------------------------------------------------------------
__launch_bounds__(256) __global__
void gat1_kernel(const float* __restrict__ xl, const float* __restrict__ xr,
                 const float* __restrict__ att, const int* __restrict__ row,
                 const int* __restrict__ deg, const int* __restrict__ csr_src,
                 float* __restrict__ agg) {
  const int n =
      __builtin_amdgcn_readfirstlane(blockIdx.x * 4 + (threadIdx.x >> 6));
  if (n >= N_NODES) return;
  const int lane = threadIdx.x & 63;
  const int r0 = __builtin_amdgcn_readfirstlane(row[n]);
  const int dg = __builtin_amdgcn_readfirstlane(deg[n]);

  const float xrv = xr[((size_t)n << 6) + lane];
  const float attv = att[lane];

  float s = 0.f, acc = 0.f;
  float xb[8];
#pragma unroll
  for (int k = 0; k < 8; ++k) {
    const int sn = ld_src(csr_src, r0 + k, k, dg);
    xb[k] = xl[((size_t)(unsigned)sn << 6) + lane];
  }
  for (int j = 0; j < dg; j += 8) {
    float xn[8];
#pragma unroll
    for (int k = 0; k < 8; ++k) {
      const int jj = j + 8 + k;
      const int sn = ld_src(csr_src, r0 + jj, jj, dg);
      xn[k] = xl[((size_t)(unsigned)sn << 6) + lane];
    }
#pragma unroll
    for (int k = 0; k < 8; ++k) {
      float v = xb[k] + xrv;
      v = fmaxf(v, 0.2f * v);  // leaky_relu
      float p = v * attv;
      p += __shfl_xor(p, 1);
      p += __shfl_xor(p, 2);
      p += __shfl_xor(p, 4);
      p += __shfl_xor(p, 8);
      p += __shfl_xor(p, 16);  // per-head sums
      float e = __expf(p);
      e = (j + k < dg) ? e : 0.f;  // wave-uniform condition
      s += e;
      acc = fmaf(e, xb[k], acc);
    }
#pragma unroll
    for (int k = 0; k < 8; ++k) xb[k] = xn[k];
  }
  const float inv = s > 0.f ? 1.f / s : 0.f;
  agg[((size_t)n << 6) + lane] = acc * inv;
}

// ---------------------------------------------------------------------------
// Layer 2 fused: H=1, C=32. Two 32-lane halves process alternating edges
// (independent s/acc, add-merge at end). Scalar src indices; per-pair
// half-select via one cndmask. 8 gathers in flight per wave.
// Epilogue: bias+relu -> h2, gate scalar inline.
// ---------------------------------------------------------------------------
__launch_bounds__(256) __global__
void gat2_kernel(const float* __restrict__ xl, const float* __restrict__ xr,
                 const float* __restrict__ att, const int* __restrict__ row,
                 const int* __restrict__ deg, const int* __restrict__ csr_src,
                 const float* __restrict__ b2, const float* __restrict__ g1w,
                 const float* __restrict__ g1b, const float* __restrict__ g2w,
                 const float* __restrict__ g2b, float* __restrict__ h2,
                 float* __restrict__ gate) {
  const int n =
      __builtin_amdgcn_readfirstlane(blockIdx.x * 4 + (threadIdx.x >> 6));
  if (n >= N_NODES) return;
  const int lane = threadIdx.x & 63;
  const int c = lane & 31;
  const int h = lane >> 5;  // half h handles edges j+h (pairs)

  const int r0 = __builtin_amdgcn_readfirstlane(row[n]);
  const int dg = __builtin_amdgcn_readfirstlane(deg[n]);

  const float xrv = xr[(size_t)n * 32 + c];
  const float attv = att[c];

  float s = 0.f, acc = 0.f;
  float xb[4];
#pragma unroll
  for (int k = 0; k < 4; ++k) {
    const int sA = ld_src(csr_src, r0 + 2 * k, 2 * k, dg);
    const int sB = ld_src(csr_src, r0 + 2 * k + 1, 2 * k + 1, dg);
    const int sel = h ? sB : sA;
    xb[k] = xl[((size_t)(unsigned)sel << 5) + c];
  }
  for (int j = 0; j < dg; j += 8) {
    float xn[4];
#pragma unroll
    for (int k = 0; k < 4; ++k) {
      const int jA = j + 8 + 2 * k;
      const int sA = ld_src(csr_src, r0 + jA, jA, dg);
      const int sB = ld_src(csr_src, r0 + jA + 1, jA + 1, dg);
      const int sel = h ? sB : sA;
      xn[k] = xl[((size_t)(unsigned)sel << 5) + c];
    }
#pragma unroll
    for (int k = 0; k < 4; ++k) {
      float v = xb[k] + xrv;
      v = fmaxf(v, 0.2f * v);
      float p = v * attv;
      p += __shfl_xor(p, 1);
      p += __shfl_xor(p, 2);
      p += __shfl_xor(p, 4);
      p += __shfl_xor(p, 8);
      p += __shfl_xor(p, 16);  // per-half (per-edge) sum
      float e = __expf(p);
      e = (j + 2 * k + h < dg) ? e : 0.f;  // per-lane (h) condition
      s += e;
      acc = fmaf(e, xb[k], acc);
    }
#pragma unroll
    for (int k = 0; k < 4; ++k) xb[k] = xn[k];
  }
  // merge halves
  const float stot = s + __shfl_xor(s, 32);
  const float atot = acc + __shfl_xor(acc, 32);
  const float inv = stot > 0.f ? 1.f / stot : 0.f;
  const float hv = fmaxf(atot * inv + b2[c], 0.f);
  if (h == 0) h2[(size_t)n * 32 + c] = hv;

  // gate = relu(hv @ g1w + g1b) . g2w + g2b (computed redundantly per half)
  float sg = g1b[c];
#pragma unroll
  for (int k = 0; k < 32; ++k)
    sg = fmaf(__shfl(hv, k, 32), g1w[k * 32 + c], sg);
  sg = fmaxf(sg, 0.f);
  float pg = sg * g2w[c];
  pg += __shfl_xor(pg, 1);
  pg += __shfl_xor(pg, 2);
  pg += __shfl_xor(pg, 4);
  pg += __shfl_xor(pg, 8);
  pg += __shfl_xor(pg, 16);
  if (lane == 0) gate[n] = pg + g2b[0];
}

// ---------------------------------------------------------------------------
// ge = exp(gate) (no-max: |gate| small); gd[g] = sum ge; pooled[g][c] = sum
// ge*h2 (division deferred to final_kernel). LDS partials per block.
// ---------------------------------------------------------------------------
__launch_bounds__(256) __global__
void gepool_kernel(const float* __restrict__ h2, const int* __restrict__ batch,
                   const float* __restrict__ gate, float* __restrict__ gd,
                   float* __restrict__ pooled) {
  __shared__ float pool[G_GRAPHS * 32];
  __shared__ float gdb[G_GRAPHS];
  const int tid = threadIdx.x;
  for (int i = tid; i < G_GRAPHS * 32; i += 256) pool[i] = 0.f;
  if (tid < G_GRAPHS) gdb[tid] = 0.f;
  __syncthreads();
  const int c = tid & 31;
  const int hw = tid >> 5;
  const int start = blockIdx.x * 256;
  const int end = min(N_NODES, start + 256);
  for (int n = start + hw; n < end; n += 8) {
    const int b = batch[n];
    const float ge = __expf(gate[n]);
    atomicAdd(&pool[b * 32 + c], ge * h2[(size_t)n * 32 + c]);
    if (c == 0) atomicAdd(&gdb[b], ge);
  }
  __syncthreads();
  for (int i = tid; i < G_GRAPHS * 32; i += 256)
    if (pool[i] != 0.f) unsafeAtomicAdd(&pooled[i], pool[i]);
  if (tid < G_GRAPHS && gdb[tid] != 0.f) unsafeAtomicAdd(&gd[tid], gdb[tid]);
}

__launch_bounds__(64) __global__
void final_kernel(const float* __restrict__ pooled, const float* __restrict__ gd,
                  const float* __restrict__ l1w, const float* __restrict__ l1b,
                  const float* __restrict__ l2w, const float* __restrict__ l2b,
                  float* __restrict__ out) {
  const int g = blockIdx.x;
  const int lane = threadIdx.x;
  if (lane >= 32) return;
  const float invgd = 1.f / gd[g];
  float s = l1b[lane];
#pragma unroll
  for (int k = 0; k < 32; ++k)
    s = fmaf(pooled[g * 32 + k] * invgd, l1w[k * 32 + lane], s);
  s = fmaxf(s, 0.f);
  float p = s * l2w[lane];
  p += __shfl_xor(p, 1);
  p += __shfl_xor(p, 2);
  p += __shfl_xor(p, 4);
  p += __shfl_xor(p, 8);
  p += __shfl_xor(p, 16);
  if (lane == 0) out[g] = p + l2b[0];
}

// ---------------------------------------------------------------------------
extern "C" void kernel_launch(void* const* d_in, const int* in_sizes, int n_in,
                              void* d_out, int out_size, void* d_ws,
                              size_t ws_size, hipStream_t stream) {
  const float* x    = (const float*)d_in[0];
  const int*   ei   = (const int*)d_in[1];
  const int*   batch= (const int*)d_in[2];
  const float* Wl1  = (const float*)d_in[3];
  const float* Wr1  = (const float*)d_in[4];
  const float* att1 = (const float*)d_in[5];
  const float* b1   = (const float*)d_in[6];
  const float* Wl2  = (const float*)d_in[7];
  const float* Wr2  = (const float*)d_in[8];
  const float* att2 = (const float*)d_in[9];
  const float* b2   = (const float*)d_in[10];
  const float* g1w  = (const float*)d_in[11];
  const float* g1b  = (const float*)d_in[12];
  const float* g2w  = (const float*)d_in[13];
  const float* g2b  = (const float*)d_in[14];
  const float* l1w  = (const float*)d_in[15];
  const float* l1b  = (const float*)d_in[16];
  const float* l2w  = (const float*)d_in[17];
  const float* l2b  = (const float*)d_in[18];
  float* out = (float*)d_out;

  // ---- workspace layout ----
  int* deg     = (int*)d_ws;          // N
  int* cursor  = deg + N_NODES;       // N
  int* row     = cursor + N_NODES;    // N
  int* bsum    = row + N_NODES;       // SCAN_BLOCKS
  int* boff    = bsum + SCAN_BLOCKS;  // SCAN_BLOCKS
  int* csr_src = boff + SCAN_BLOCKS;  // E + 16 pad (branch-free prefetch)
  float* fbase = (float*)(csr_src + N_EDGES + 16);
  float* xl1  = fbase;                         // N*64
  float* xr1  = xl1 + (size_t)N_NODES * 64;    // N*64
  float* agg1 = xr1 + (size_t)N_NODES * 64;    // N*64
  float* gate = agg1 + (size_t)N_NODES * 64;   // N
  float* gd   = gate + N_NODES;                // 64
  float* pooled = gd + G_GRAPHS;               // 64*32
  // layer-2 aliases (xl1/xr1 dead by the time these are written)
  float* xl2 = xl1;                            // N*32
  float* xr2 = xl1 + (size_t)N_NODES * 32;     // N*32
  float* h2  = xr1;                            // N*32

  hipMemsetAsync(deg, 0, (size_t)N_NODES * sizeof(int), stream);
  hipMemsetAsync(gd, 0, (size_t)(G_GRAPHS + G_GRAPHS * 32) * sizeof(float), stream);

  // CSR build (shared by both layers)
  hist_kernel<<<(N_EDGES + 255) / 256, 256, 0, stream>>>(ei, deg);
  scan1_kernel<<<SCAN_BLOCKS, 256, 0, stream>>>(deg, bsum);
  scan2_kernel<<<1, 128, 0, stream>>>(bsum, boff);
  scan3_kernel<<<SCAN_BLOCKS, 256, 0, stream>>>(deg, boff, row, cursor);
  scatter_kernel<<<(N_EDGES + 255) / 256, 256, 0, stream>>>(ei, cursor, csr_src);

  // Layer 1
  gemm_dual<128, 64, false><<<(N_NODES + 31) / 32, 256, 0, stream>>>(
      x, Wl1, Wr1, nullptr, xl1, xr1, N_NODES);
  gat1_kernel<<<(N_NODES + 3) / 4, 256, 0, stream>>>(xl1, xr1, att1, row, deg,
                                                     csr_src, agg1);

  // Layer 2 (bias1+relu fused into A-load; gate fused into epilogue)
  gemm_dual<64, 32, true><<<(N_NODES + 31) / 32, 256, 0, stream>>>(
      agg1, Wl2, Wr2, b1, xl2, xr2, N_NODES);
  gat2_kernel<<<(N_NODES + 3) / 4, 256, 0, stream>>>(
      xl2, xr2, att2, row, deg, csr_src, b2, g1w, g1b, g2w, g2b, h2, gate);

  // Pooling + head (no-max graph softmax)
  gepool_kernel<<<(N_NODES + 255) / 256, 256, 0, stream>>>(h2, batch, gate, gd,
                                                           pooled);
  final_kernel<<<64, 64, 0, stream>>>(pooled, gd, l1w, l1b, l2w, l2b, out);
}

// Round 8
// 571.704 us; speedup vs baseline: 1.1768x; 1.1021x over previous
//
#include <hip/hip_runtime.h>
#include <cfloat>
#include <cstdint>
#include <cstddef>

#define N_NODES 100000
#define N_EDGES 1600000
#define G_GRAPHS 64
#define SCAN_CHUNK 1024
#define SCAN_BLOCKS ((N_NODES + SCAN_CHUNK - 1) / SCAN_CHUNK)  // 98
#define BKT_SHIFT 9
#define BKT_NODES (1 << BKT_SHIFT)                              // 512
#define NBKT ((N_NODES + BKT_NODES - 1) >> BKT_SHIFT)           // 196

// Load a (possibly past-end, padded) csr entry, select 0 if beyond dg, and
// force the result into an SGPR.
__device__ __forceinline__ int ld_src(const int* __restrict__ p, int idx,
                                      int i, int lim) {
  int v = p[idx];
  v = (i < lim) ? v : 0;
  return __builtin_amdgcn_readfirstlane(v);
}

// ---------------------------------------------------------------------------
// Dual GEMM: O0 = act(A) @ W0, O1 = act(A) @ W1.  A:[n,K], W:[K,J].
// act = relu(A + bias) when FUSE.  A-tile LDS reads vectorized (b128).
// ---------------------------------------------------------------------------
template <int K, int J, bool FUSE>
__launch_bounds__(256) __global__
void gemm_dual(const float* __restrict__ A, const float* __restrict__ W0,
               const float* __restrict__ W1, const float* __restrict__ bias,
               float* __restrict__ O0, float* __restrict__ O1, int n) {
  constexpr int CPT = J / 32;
  __shared__ __align__(16) float As[32][K];
  __shared__ __align__(16) float Ws[K][J];
  const int tid = threadIdx.x;
  const int n0 = blockIdx.x * 32;

  constexpr int AV = 32 * K / 4;
  for (int i = tid; i < AV; i += 256) {
    const int node = i / (K / 4);
    const int kg = i % (K / 4);
    float4 v = make_float4(0.f, 0.f, 0.f, 0.f);
    if (n0 + node < n) {
      v = reinterpret_cast<const float4*>(A)[(size_t)(n0 + node) * (K / 4) + kg];
      if constexpr (FUSE) {
        const float4 b = reinterpret_cast<const float4*>(bias)[kg];
        v.x = fmaxf(v.x + b.x, 0.f);
        v.y = fmaxf(v.y + b.y, 0.f);
        v.z = fmaxf(v.z + b.z, 0.f);
        v.w = fmaxf(v.w + b.w, 0.f);
      }
    }
    reinterpret_cast<float4*>(&As[node][0])[kg] = v;
  }

  const int tr = tid >> 5;
  const int tc = tid & 31;

  for (int mm = 0; mm < 2; ++mm) {
    const float* __restrict__ W = mm ? W1 : W0;
    float* __restrict__ O = mm ? O1 : O0;
    for (int i = tid; i < K * J / 4; i += 256)
      reinterpret_cast<float4*>(&Ws[0][0])[i] =
          reinterpret_cast<const float4*>(W)[i];
    __syncthreads();

    float acc[4][CPT];
#pragma unroll
    for (int i = 0; i < 4; ++i)
#pragma unroll
      for (int j = 0; j < CPT; ++j) acc[i][j] = 0.f;

#pragma unroll 4
    for (int k4 = 0; k4 < K / 4; ++k4) {
      float a[4][4];
#pragma unroll
      for (int i = 0; i < 4; ++i) {
        const float4 t =
            reinterpret_cast<const float4*>(&As[tr * 4 + i][0])[k4];
        a[i][0] = t.x; a[i][1] = t.y; a[i][2] = t.z; a[i][3] = t.w;
      }
#pragma unroll
      for (int kk = 0; kk < 4; ++kk) {
        const int k = k4 * 4 + kk;
        float w[CPT];
#pragma unroll
        for (int j = 0; j < CPT; ++j) w[j] = Ws[k][tc + 32 * j];
#pragma unroll
        for (int i = 0; i < 4; ++i)
#pragma unroll
          for (int j = 0; j < CPT; ++j)
            acc[i][j] = fmaf(a[i][kk], w[j], acc[i][j]);
      }
    }

#pragma unroll
    for (int i = 0; i < 4; ++i) {
      const int node = n0 + tr * 4 + i;
      if (node < n)
#pragma unroll
        for (int j = 0; j < CPT; ++j)
          O[(size_t)node * J + tc + 32 * j] = acc[i][j];
    }
    __syncthreads();
  }
}

// ---------------------------------------------------------------------------
// CSR build: fused deg+bucket hist -> node scan -> bucket scan ->
// two-phase partition (bucket staging, then per-bucket local scatter).
// ---------------------------------------------------------------------------
__launch_bounds__(256) __global__
void hist_kernel(const int* __restrict__ ei, int* __restrict__ deg,
                 int* __restrict__ bhist) {
  __shared__ int lb[NBKT];
  for (int i = threadIdx.x; i < NBKT; i += 256) lb[i] = 0;
  __syncthreads();
  const int e0 = blockIdx.x * 1024 + threadIdx.x;
#pragma unroll
  for (int k = 0; k < 4; ++k) {
    const int e = e0 + k * 256;
    if (e < N_EDGES) {
      const int dst = ei[N_EDGES + e];
      atomicAdd(&deg[dst], 1);
      atomicAdd(&lb[dst >> BKT_SHIFT], 1);
    }
  }
  __syncthreads();
  for (int i = threadIdx.x; i < NBKT; i += 256)
    if (lb[i]) atomicAdd(&bhist[i], lb[i]);
}

__launch_bounds__(256) __global__
void scan1_kernel(const int* __restrict__ deg, int* __restrict__ bsum) {
  __shared__ int ls[256];
  const int tid = threadIdx.x;
  const int base = blockIdx.x * SCAN_CHUNK + tid * 4;
  int s = 0;
  if (base + 3 < N_NODES) {
    const int4 v = reinterpret_cast<const int4*>(deg)[base >> 2];
    s = v.x + v.y + v.z + v.w;
  } else {
#pragma unroll
    for (int k = 0; k < 4; ++k)
      if (base + k < N_NODES) s += deg[base + k];
  }
  ls[tid] = s;
  __syncthreads();
  for (int d = 128; d > 0; d >>= 1) {
    if (tid < d) ls[tid] += ls[tid + d];
    __syncthreads();
  }
  if (tid == 0) bsum[blockIdx.x] = ls[0];
}

__launch_bounds__(128) __global__
void scan2_kernel(const int* __restrict__ bsum, int* __restrict__ boff) {
  __shared__ int ls[128];
  const int tid = threadIdx.x;
  const int v = (tid < SCAN_BLOCKS) ? bsum[tid] : 0;
  ls[tid] = v;
  __syncthreads();
  for (int d = 1; d < 128; d <<= 1) {
    const int t = (tid >= d) ? ls[tid - d] : 0;
    __syncthreads();
    ls[tid] += t;
    __syncthreads();
  }
  if (tid < SCAN_BLOCKS) boff[tid] = ls[tid] - v;
}

__launch_bounds__(256) __global__
void scan3_kernel(const int* __restrict__ deg, const int* __restrict__ boff,
                  int* __restrict__ row) {
  __shared__ int ls[256];
  const int tid = threadIdx.x;
  const int base = blockIdx.x * SCAN_CHUNK + tid * 4;
  int4 v = make_int4(0, 0, 0, 0);
  if (base + 3 < N_NODES) {
    v = reinterpret_cast<const int4*>(deg)[base >> 2];
  } else {
    if (base + 0 < N_NODES) v.x = deg[base + 0];
    if (base + 1 < N_NODES) v.y = deg[base + 1];
    if (base + 2 < N_NODES) v.z = deg[base + 2];
    if (base + 3 < N_NODES) v.w = deg[base + 3];
  }
  const int s = v.x + v.y + v.z + v.w;
  ls[tid] = s;
  __syncthreads();
  for (int d = 1; d < 256; d <<= 1) {
    const int t = (tid >= d) ? ls[tid - d] : 0;
    __syncthreads();
    ls[tid] += t;
    __syncthreads();
  }
  const int run = ls[tid] - s + boff[blockIdx.x];
  const int4 r = make_int4(run, run + v.x, run + v.x + v.y,
                           run + v.x + v.y + v.z);
  if (base + 3 < N_NODES) {
    reinterpret_cast<int4*>(row)[base >> 2] = r;
  } else {
    if (base + 0 < N_NODES) row[base + 0] = r.x;
    if (base + 1 < N_NODES) row[base + 1] = r.y;
    if (base + 2 < N_NODES) row[base + 2] = r.z;
    if (base + 3 < N_NODES) row[base + 3] = r.w;
  }
}

__launch_bounds__(256) __global__
void bscan_kernel(const int* __restrict__ bhist, int* __restrict__ bbase,
                  int* __restrict__ bcursor) {
  __shared__ int ls[256];
  const int tid = threadIdx.x;
  const int v = (tid < NBKT) ? bhist[tid] : 0;
  ls[tid] = v;
  __syncthreads();
  for (int d = 1; d < 256; d <<= 1) {
    const int t = (tid >= d) ? ls[tid - d] : 0;
    __syncthreads();
    ls[tid] += t;
    __syncthreads();
  }
  if (tid < NBKT) {
    const int ex = ls[tid] - v;
    bbase[tid] = ex;
    bcursor[tid] = ex;
  }
}

// phase A: scatter edges into bucket-contiguous staging (dense writes).
__launch_bounds__(1024) __global__
void partA_kernel(const int* __restrict__ ei, int* __restrict__ bcursor,
                  int2* __restrict__ staging) {
  __shared__ int lh[NBKT];
  __shared__ int lbase[NBKT];
  const int tid = threadIdx.x;
  for (int i = tid; i < NBKT; i += 1024) lh[i] = 0;
  __syncthreads();
  const int e0 = blockIdx.x * 4096 + tid;
  int s[4], d[4];
#pragma unroll
  for (int k = 0; k < 4; ++k) {
    const int e = e0 + k * 1024;
    const bool ok = e < N_EDGES;
    s[k] = ok ? ei[e] : 0;
    d[k] = ok ? ei[N_EDGES + e] : -1;
    if (ok) atomicAdd(&lh[d[k] >> BKT_SHIFT], 1);
  }
  __syncthreads();
  for (int i = tid; i < NBKT; i += 1024) {
    const int c = lh[i];
    lbase[i] = c ? atomicAdd(&bcursor[i], c) : 0;
    lh[i] = 0;
  }
  __syncthreads();
#pragma unroll
  for (int k = 0; k < 4; ++k) {
    if (d[k] >= 0) {
      const int b = d[k] >> BKT_SHIFT;
      const int p = lbase[b] + atomicAdd(&lh[b], 1);
      staging[p] = make_int2(s[k], d[k]);
    }
  }
}

// phase B: per-bucket local scatter into final CSR (32KB write window).
__launch_bounds__(256) __global__
void partB_kernel(const int2* __restrict__ staging,
                  const int* __restrict__ bbase, const int* __restrict__ bhist,
                  const int* __restrict__ row, int* __restrict__ csr_src) {
  __shared__ int lcur[BKT_NODES];
  const int b = blockIdx.x;
  const int node0 = b << BKT_SHIFT;
  for (int i = threadIdx.x; i < BKT_NODES; i += 256) {
    const int n = node0 + i;
    lcur[i] = (n < N_NODES) ? row[n] : 0;
  }
  __syncthreads();
  const int start = bbase[b];
  const int cnt = bhist[b];
  for (int i = threadIdx.x; i < cnt; i += 256) {
    const int2 e = staging[start + i];
    const int p = atomicAdd(&lcur[e.y - node0], 1);
    csr_src[p] = e.x;
  }
}

// ---------------------------------------------------------------------------
// Layer 1 fused softmax-aggregate. H=2, C=32. One wave per node.
// Scalar (SGPR) src indices; 8 gathers in flight.
// ---------------------------------------------------------------------------
__launch_bounds__(256) __global__
void gat1_kernel(const float* __restrict__ xl, const float* __restrict__ xr,
                 const float* __restrict__ att, const int* __restrict__ row,
                 const int* __restrict__ deg, const int* __restrict__ csr_src,
                 float* __restrict__ agg) {
  const int n =
      __builtin_amdgcn_readfirstlane(blockIdx.x * 4 + (threadIdx.x >> 6));
  if (n >= N_NODES) return;
  const int lane = threadIdx.x & 63;
  const int r0 = __builtin_amdgcn_readfirstlane(row[n]);
  const int dg = __builtin_amdgcn_readfirstlane(deg[n]);

  const float xrv = xr[((size_t)n << 6) + lane];
  const float attv = att[lane];

  float s = 0.f, acc = 0.f;
  float xb[8];
#pragma unroll
  for (int k = 0; k < 8; ++k) {
    const int sn = ld_src(csr_src, r0 + k, k, dg);
    xb[k] = xl[((size_t)(unsigned)sn << 6) + lane];
  }
  for (int j = 0; j < dg; j += 8) {
    float xn[8];
#pragma unroll
    for (int k = 0; k < 8; ++k) {
      const int jj = j + 8 + k;
      const int sn = ld_src(csr_src, r0 + jj, jj, dg);
      xn[k] = xl[((size_t)(unsigned)sn << 6) + lane];
    }
#pragma unroll
    for (int k = 0; k < 8; ++k) {
      float v = xb[k] + xrv;
      v = fmaxf(v, 0.2f * v);  // leaky_relu
      float p = v * attv;
      p += __shfl_xor(p, 1);
      p += __shfl_xor(p, 2);
      p += __shfl_xor(p, 4);
      p += __shfl_xor(p, 8);
      p += __shfl_xor(p, 16);  // per-head sums
      float e = __expf(p);
      e = (j + k < dg) ? e : 0.f;
      s += e;
      acc = fmaf(e, xb[k], acc);
    }
#pragma unroll
    for (int k = 0; k < 8; ++k) xb[k] = xn[k];
  }
  const float inv = s > 0.f ? 1.f / s : 0.f;
  agg[((size_t)n << 6) + lane] = acc * inv;
}

// ---------------------------------------------------------------------------
// Layer 2 fused: H=1, C=32. Two 32-lane halves, alternating edges, scalar
// src indices, 8 gathers in flight. Epilogue: bias+relu -> h2, gate inline.
// ---------------------------------------------------------------------------
__launch_bounds__(256) __global__
void gat2_kernel(const float* __restrict__ xl, const float* __restrict__ xr,
                 const float* __restrict__ att, const int* __restrict__ row,
                 const int* __restrict__ deg, const int* __restrict__ csr_src,
                 const float* __restrict__ b2, const float* __restrict__ g1w,
                 const float* __restrict__ g1b, const float* __restrict__ g2w,
                 const float* __restrict__ g2b, float* __restrict__ h2,
                 float* __restrict__ gate) {
  const int n =
      __builtin_amdgcn_readfirstlane(blockIdx.x * 4 + (threadIdx.x >> 6));
  if (n >= N_NODES) return;
  const int lane = threadIdx.x & 63;
  const int c = lane & 31;
  const int h = lane >> 5;

  const int r0 = __builtin_amdgcn_readfirstlane(row[n]);
  const int dg = __builtin_amdgcn_readfirstlane(deg[n]);

  const float xrv = xr[(size_t)n * 32 + c];
  const float attv = att[c];

  float s = 0.f, acc = 0.f;
  float xb[4];
#pragma unroll
  for (int k = 0; k < 4; ++k) {
    const int sA = ld_src(csr_src, r0 + 2 * k, 2 * k, dg);
    const int sB = ld_src(csr_src, r0 + 2 * k + 1, 2 * k + 1, dg);
    const int sel = h ? sB : sA;
    xb[k] = xl[((size_t)(unsigned)sel << 5) + c];
  }
  for (int j = 0; j < dg; j += 8) {
    float xn[4];
#pragma unroll
    for (int k = 0; k < 4; ++k) {
      const int jA = j + 8 + 2 * k;
      const int sA = ld_src(csr_src, r0 + jA, jA, dg);
      const int sB = ld_src(csr_src, r0 + jA + 1, jA + 1, dg);
      const int sel = h ? sB : sA;
      xn[k] = xl[((size_t)(unsigned)sel << 5) + c];
    }
#pragma unroll
    for (int k = 0; k < 4; ++k) {
      float v = xb[k] + xrv;
      v = fmaxf(v, 0.2f * v);
      float p = v * attv;
      p += __shfl_xor(p, 1);
      p += __shfl_xor(p, 2);
      p += __shfl_xor(p, 4);
      p += __shfl_xor(p, 8);
      p += __shfl_xor(p, 16);
      float e = __expf(p);
      e = (j + 2 * k + h < dg) ? e : 0.f;
      s += e;
      acc = fmaf(e, xb[k], acc);
    }
#pragma unroll
    for (int k = 0; k < 4; ++k) xb[k] = xn[k];
  }
  const float stot = s + __shfl_xor(s, 32);
  const float atot = acc + __shfl_xor(acc, 32);
  const float inv = stot > 0.f ? 1.f / stot : 0.f;
  const float hv = fmaxf(atot * inv + b2[c], 0.f);
  if (h == 0) h2[(size_t)n * 32 + c] = hv;

  float sg = g1b[c];
#pragma unroll
  for (int k = 0; k < 32; ++k)
    sg = fmaf(__shfl(hv, k, 32), g1w[k * 32 + c], sg);
  sg = fmaxf(sg, 0.f);
  float pg = sg * g2w[c];
  pg += __shfl_xor(pg, 1);
  pg += __shfl_xor(pg, 2);
  pg += __shfl_xor(pg, 4);
  pg += __shfl_xor(pg, 8);
  pg += __shfl_xor(pg, 16);
  if (lane == 0) gate[n] = pg + g2b[0];
}

// ---------------------------------------------------------------------------
__launch_bounds__(256) __global__
void gepool_kernel(const float* __restrict__ h2, const int* __restrict__ batch,
                   const float* __restrict__ gate, float* __restrict__ gd,
                   float* __restrict__ pooled) {
  __shared__ float pool[G_GRAPHS * 32];
  __shared__ float gdb[G_GRAPHS];
  const int tid = threadIdx.x;
  for (int i = tid; i < G_GRAPHS * 32; i += 256) pool[i] = 0.f;
  if (tid < G_GRAPHS) gdb[tid] = 0.f;
  __syncthreads();
  const int c = tid & 31;
  const int hw = tid >> 5;
  const int start = blockIdx.x * 256;
  const int end = min(N_NODES, start + 256);
  for (int n = start + hw; n < end; n += 8) {
    const int b = batch[n];
    const float ge = __expf(gate[n]);
    atomicAdd(&pool[b * 32 + c], ge * h2[(size_t)n * 32 + c]);
    if (c == 0) atomicAdd(&gdb[b], ge);
  }
  __syncthreads();
  for (int i = tid; i < G_GRAPHS * 32; i += 256)
    if (pool[i] != 0.f) unsafeAtomicAdd(&pooled[i], pool[i]);
  if (tid < G_GRAPHS && gdb[tid] != 0.f) unsafeAtomicAdd(&gd[tid], gdb[tid]);
}

__launch_bounds__(64) __global__
void final_kernel(const float* __restrict__ pooled, const float* __restrict__ gd,
                  const float* __restrict__ l1w, const float* __restrict__ l1b,
                  const float* __restrict__ l2w, const float* __restrict__ l2b,
                  float* __restrict__ out) {
  const int g = blockIdx.x;
  const int lane = threadIdx.x;
  if (lane >= 32) return;
  const float invgd = 1.f / gd[g];
  float s = l1b[lane];
#pragma unroll
  for (int k = 0; k < 32; ++k)
    s = fmaf(pooled[g * 32 + k] * invgd, l1w[k * 32 + lane], s);
  s = fmaxf(s, 0.f);
  float p = s * l2w[lane];
  p += __shfl_xor(p, 1);
  p += __shfl_xor(p, 2);
  p += __shfl_xor(p, 4);
  p += __shfl_xor(p, 8);
  p += __shfl_xor(p, 16);
  if (lane == 0) out[g] = p + l2b[0];
}

// ---------------------------------------------------------------------------
extern "C" void kernel_launch(void* const* d_in, const int* in_sizes, int n_in,
                              void* d_out, int out_size, void* d_ws,
                              size_t ws_size, hipStream_t stream) {
  const float* x    = (const float*)d_in[0];
  const int*   ei   = (const int*)d_in[1];
  const int*   batch= (const int*)d_in[2];
  const float* Wl1  = (const float*)d_in[3];
  const float* Wr1  = (const float*)d_in[4];
  const float* att1 = (const float*)d_in[5];
  const float* b1   = (const float*)d_in[6];
  const float* Wl2  = (const float*)d_in[7];
  const float* Wr2  = (const float*)d_in[8];
  const float* att2 = (const float*)d_in[9];
  const float* b2   = (const float*)d_in[10];
  const float* g1w  = (const float*)d_in[11];
  const float* g1b  = (const float*)d_in[12];
  const float* g2w  = (const float*)d_in[13];
  const float* g2b  = (const float*)d_in[14];
  const float* l1w  = (const float*)d_in[15];
  const float* l1b  = (const float*)d_in[16];
  const float* l2w  = (const float*)d_in[17];
  const float* l2b  = (const float*)d_in[18];
  float* out = (float*)d_out;

  // ---- workspace layout (ints first; staging 8B-aligned) ----
  int* deg     = (int*)d_ws;            // N        (zeroed)
  int* bhist   = deg + N_NODES;         // NBKT     (zeroed, adjacent)
  int* row     = bhist + NBKT;          // N
  int* bsum    = row + N_NODES;         // SCAN_BLOCKS
  int* boff    = bsum + SCAN_BLOCKS;    // SCAN_BLOCKS
  int* bbase   = boff + SCAN_BLOCKS;    // NBKT
  int* bcursor = bbase + NBKT;          // NBKT
  int* csr_src = bcursor + NBKT;        // E + 16 pad
  int2* staging = (int2*)(csr_src + N_EDGES + 16);  // E int2
  float* fbase = (float*)(staging + N_EDGES);
  float* xl1  = fbase;                         // N*64
  float* xr1  = xl1 + (size_t)N_NODES * 64;    // N*64
  float* agg1 = xr1 + (size_t)N_NODES * 64;    // N*64
  float* gate = agg1 + (size_t)N_NODES * 64;   // N
  float* gd   = gate + N_NODES;                // 64
  float* pooled = gd + G_GRAPHS;               // 64*32
  // layer-2 aliases
  float* xl2 = xl1;                            // N*32
  float* xr2 = xl1 + (size_t)N_NODES * 32;     // N*32
  float* h2  = xr1;                            // N*32

  hipMemsetAsync(deg, 0, (size_t)(N_NODES + NBKT) * sizeof(int), stream);
  hipMemsetAsync(gd, 0, (size_t)(G_GRAPHS + G_GRAPHS * 32) * sizeof(float), stream);

  // CSR build (two-phase partition; shared by both layers)
  hist_kernel<<<(N_EDGES + 1023) / 1024, 256, 0, stream>>>(ei, deg, bhist);
  scan1_kernel<<<SCAN_BLOCKS, 256, 0, stream>>>(deg, bsum);
  scan2_kernel<<<1, 128, 0, stream>>>(bsum, boff);
  scan3_kernel<<<SCAN_BLOCKS, 256, 0, stream>>>(deg, boff, row);
  bscan_kernel<<<1, 256, 0, stream>>>(bhist, bbase, bcursor);
  partA_kernel<<<(N_EDGES + 4095) / 4096, 1024, 0, stream>>>(ei, bcursor,
                                                             staging);
  partB_kernel<<<NBKT, 256, 0, stream>>>(staging, bbase, bhist, row, csr_src);

  // Layer 1
  gemm_dual<128, 64, false><<<(N_NODES + 31) / 32, 256, 0, stream>>>(
      x, Wl1, Wr1, nullptr, xl1, xr1, N_NODES);
  gat1_kernel<<<(N_NODES + 3) / 4, 256, 0, stream>>>(xl1, xr1, att1, row, deg,
                                                     csr_src, agg1);

  // Layer 2 (bias1+relu fused into A-load; gate fused into epilogue)
  gemm_dual<64, 32, true><<<(N_NODES + 31) / 32, 256, 0, stream>>>(
      agg1, Wl2, Wr2, b1, xl2, xr2, N_NODES);
  gat2_kernel<<<(N_NODES + 3) / 4, 256, 0, stream>>>(
      xl2, xr2, att2, row, deg, csr_src, b2, g1w, g1b, g2w, g2b, h2, gate);

  // Pooling + head (no-max graph softmax)
  gepool_kernel<<<(N_NODES + 255) / 256, 256, 0, stream>>>(h2, batch, gate, gd,
                                                           pooled);
  final_kernel<<<64, 64, 0, stream>>>(pooled, gd, l1w, l1b, l2w, l2b, out);
}

// Round 9
// 549.722 us; speedup vs baseline: 1.2239x; 1.0400x over previous
//
#include <hip/hip_runtime.h>
#include <hip/hip_fp16.h>
#include <cfloat>
#include <cstdint>
#include <cstddef>

#define N_NODES 100000
#define N_EDGES 1600000
#define G_GRAPHS 64
#define SCAN_CHUNK 1024
#define SCAN_BLOCKS ((N_NODES + SCAN_CHUNK - 1) / SCAN_CHUNK)  // 98
#define BKT_SHIFT 9
#define BKT_NODES (1 << BKT_SHIFT)                              // 512
#define NBKT ((N_NODES + BKT_NODES - 1) >> BKT_SHIFT)           // 196

// Load a (possibly past-end, padded) csr entry, select 0 if beyond dg, and
// force the result into an SGPR.
__device__ __forceinline__ int ld_src(const int* __restrict__ p, int idx,
                                      int i, int lim) {
  int v = p[idx];
  v = (i < lim) ? v : 0;
  return __builtin_amdgcn_readfirstlane(v);
}

// ---------------------------------------------------------------------------
// Dual GEMM, single-pass: O0 = act(A)@W0 (fp16 if HALF0), O1 = act(A)@W1.
// A:[n,K], W:[K,J]. act = relu(A+bias) when FUSE. Both W tiles LDS-resident,
// transposed+padded for ds_read_b128; A-loads reused for both accumulators.
// ---------------------------------------------------------------------------
template <int K, int J, bool FUSE, bool HALF0>
__launch_bounds__(256) __global__
void gemm_dual(const float* __restrict__ A, const float* __restrict__ W0,
               const float* __restrict__ W1, const float* __restrict__ bias,
               void* __restrict__ O0v, float* __restrict__ O1, int n) {
  constexpr int BK = 64;
  constexpr int CPT = J / 32;
  __shared__ __align__(16) float As[32][BK];
  __shared__ __align__(16) float W0t[J][BK + 4];
  __shared__ __align__(16) float W1t[J][BK + 4];
  const int tid = threadIdx.x;
  const int n0 = blockIdx.x * 32;
  const int tr = tid >> 5;
  const int tc = tid & 31;

  float acc[4][CPT][2];
#pragma unroll
  for (int i = 0; i < 4; ++i)
#pragma unroll
    for (int j = 0; j < CPT; ++j) {
      acc[i][j][0] = 0.f;
      acc[i][j][1] = 0.f;
    }

  for (int kc = 0; kc < K; kc += BK) {
    // stage A tile (32 x BK), float4, fused bias+relu if FUSE
    for (int i = tid; i < 32 * BK / 4; i += 256) {
      const int node = i / (BK / 4);
      const int kg = i % (BK / 4);
      float4 v = make_float4(0.f, 0.f, 0.f, 0.f);
      if (n0 + node < n) {
        v = reinterpret_cast<const float4*>(
            A)[(size_t)(n0 + node) * (K / 4) + kc / 4 + kg];
        if constexpr (FUSE) {
          const float4 b =
              reinterpret_cast<const float4*>(bias)[kc / 4 + kg];
          v.x = fmaxf(v.x + b.x, 0.f);
          v.y = fmaxf(v.y + b.y, 0.f);
          v.z = fmaxf(v.z + b.z, 0.f);
          v.w = fmaxf(v.w + b.w, 0.f);
        }
      }
      reinterpret_cast<float4*>(&As[node][0])[kg] = v;
    }
    // stage both W tiles, transposed (coalesced global read)
    for (int i = tid; i < BK * J; i += 256) {
      const int k = i / J;
      const int j = i % J;
      W0t[j][k] = W0[(size_t)(kc + k) * J + j];
      W1t[j][k] = W1[(size_t)(kc + k) * J + j];
    }
    __syncthreads();

#pragma unroll 2
    for (int k4 = 0; k4 < BK / 4; ++k4) {
      float4 a[4];
#pragma unroll
      for (int i = 0; i < 4; ++i)
        a[i] = reinterpret_cast<const float4*>(&As[tr * 4 + i][0])[k4];
      float4 w0[CPT], w1[CPT];
#pragma unroll
      for (int j = 0; j < CPT; ++j) {
        w0[j] = *reinterpret_cast<const float4*>(&W0t[tc + 32 * j][k4 * 4]);
        w1[j] = *reinterpret_cast<const float4*>(&W1t[tc + 32 * j][k4 * 4]);
      }
#pragma unroll
      for (int i = 0; i < 4; ++i)
#pragma unroll
        for (int j = 0; j < CPT; ++j) {
          acc[i][j][0] = fmaf(a[i].x, w0[j].x, acc[i][j][0]);
          acc[i][j][0] = fmaf(a[i].y, w0[j].y, acc[i][j][0]);
          acc[i][j][0] = fmaf(a[i].z, w0[j].z, acc[i][j][0]);
          acc[i][j][0] = fmaf(a[i].w, w0[j].w, acc[i][j][0]);
          acc[i][j][1] = fmaf(a[i].x, w1[j].x, acc[i][j][1]);
          acc[i][j][1] = fmaf(a[i].y, w1[j].y, acc[i][j][1]);
          acc[i][j][1] = fmaf(a[i].z, w1[j].z, acc[i][j][1]);
          acc[i][j][1] = fmaf(a[i].w, w1[j].w, acc[i][j][1]);
        }
    }
    __syncthreads();
  }

#pragma unroll
  for (int i = 0; i < 4; ++i) {
    const int node = n0 + tr * 4 + i;
    if (node < n) {
      if constexpr (HALF0) {
        __half* O0 = (__half*)O0v;
#pragma unroll
        for (int j = 0; j < CPT; ++j)
          O0[(size_t)node * J + tc + 32 * j] = __float2half(acc[i][j][0]);
      } else {
        float* O0 = (float*)O0v;
#pragma unroll
        for (int j = 0; j < CPT; ++j)
          O0[(size_t)node * J + tc + 32 * j] = acc[i][j][0];
      }
#pragma unroll
      for (int j = 0; j < CPT; ++j)
        O1[(size_t)node * J + tc + 32 * j] = acc[i][j][1];
    }
  }
}

// ---------------------------------------------------------------------------
// CSR build: fused deg+bucket hist -> node scan -> bucket scan ->
// two-phase partition (bucket staging, then per-bucket local scatter).
// ---------------------------------------------------------------------------
__launch_bounds__(256) __global__
void hist_kernel(const int* __restrict__ ei, int* __restrict__ deg,
                 int* __restrict__ bhist) {
  __shared__ int lb[NBKT];
  for (int i = threadIdx.x; i < NBKT; i += 256) lb[i] = 0;
  __syncthreads();
  const int e0 = blockIdx.x * 1024 + threadIdx.x;
#pragma unroll
  for (int k = 0; k < 4; ++k) {
    const int e = e0 + k * 256;
    if (e < N_EDGES) {
      const int dst = ei[N_EDGES + e];
      atomicAdd(&deg[dst], 1);
      atomicAdd(&lb[dst >> BKT_SHIFT], 1);
    }
  }
  __syncthreads();
  for (int i = threadIdx.x; i < NBKT; i += 256)
    if (lb[i]) atomicAdd(&bhist[i], lb[i]);
}

__launch_bounds__(256) __global__
void scan1_kernel(const int* __restrict__ deg, int* __restrict__ bsum) {
  __shared__ int ls[256];
  const int tid = threadIdx.x;
  const int base = blockIdx.x * SCAN_CHUNK + tid * 4;
  int s = 0;
  if (base + 3 < N_NODES) {
    const int4 v = reinterpret_cast<const int4*>(deg)[base >> 2];
    s = v.x + v.y + v.z + v.w;
  } else {
#pragma unroll
    for (int k = 0; k < 4; ++k)
      if (base + k < N_NODES) s += deg[base + k];
  }
  ls[tid] = s;
  __syncthreads();
  for (int d = 128; d > 0; d >>= 1) {
    if (tid < d) ls[tid] += ls[tid + d];
    __syncthreads();
  }
  if (tid == 0) bsum[blockIdx.x] = ls[0];
}

__launch_bounds__(128) __global__
void scan2_kernel(const int* __restrict__ bsum, int* __restrict__ boff) {
  __shared__ int ls[128];
  const int tid = threadIdx.x;
  const int v = (tid < SCAN_BLOCKS) ? bsum[tid] : 0;
  ls[tid] = v;
  __syncthreads();
  for (int d = 1; d < 128; d <<= 1) {
    const int t = (tid >= d) ? ls[tid - d] : 0;
    __syncthreads();
    ls[tid] += t;
    __syncthreads();
  }
  if (tid < SCAN_BLOCKS) boff[tid] = ls[tid] - v;
}

__launch_bounds__(256) __global__
void scan3_kernel(const int* __restrict__ deg, const int* __restrict__ boff,
                  int* __restrict__ row) {
  __shared__ int ls[256];
  const int tid = threadIdx.x;
  const int base = blockIdx.x * SCAN_CHUNK + tid * 4;
  int4 v = make_int4(0, 0, 0, 0);
  if (base + 3 < N_NODES) {
    v = reinterpret_cast<const int4*>(deg)[base >> 2];
  } else {
    if (base + 0 < N_NODES) v.x = deg[base + 0];
    if (base + 1 < N_NODES) v.y = deg[base + 1];
    if (base + 2 < N_NODES) v.z = deg[base + 2];
    if (base + 3 < N_NODES) v.w = deg[base + 3];
  }
  const int s = v.x + v.y + v.z + v.w;
  ls[tid] = s;
  __syncthreads();
  for (int d = 1; d < 256; d <<= 1) {
    const int t = (tid >= d) ? ls[tid - d] : 0;
    __syncthreads();
    ls[tid] += t;
    __syncthreads();
  }
  const int run = ls[tid] - s + boff[blockIdx.x];
  const int4 r = make_int4(run, run + v.x, run + v.x + v.y,
                           run + v.x + v.y + v.z);
  if (base + 3 < N_NODES) {
    reinterpret_cast<int4*>(row)[base >> 2] = r;
  } else {
    if (base + 0 < N_NODES) row[base + 0] = r.x;
    if (base + 1 < N_NODES) row[base + 1] = r.y;
    if (base + 2 < N_NODES) row[base + 2] = r.z;
    if (base + 3 < N_NODES) row[base + 3] = r.w;
  }
}

__launch_bounds__(256) __global__
void bscan_kernel(const int* __restrict__ bhist, int* __restrict__ bbase,
                  int* __restrict__ bcursor) {
  __shared__ int ls[256];
  const int tid = threadIdx.x;
  const int v = (tid < NBKT) ? bhist[tid] : 0;
  ls[tid] = v;
  __syncthreads();
  for (int d = 1; d < 256; d <<= 1) {
    const int t = (tid >= d) ? ls[tid - d] : 0;
    __syncthreads();
    ls[tid] += t;
    __syncthreads();
  }
  if (tid < NBKT) {
    const int ex = ls[tid] - v;
    bbase[tid] = ex;
    bcursor[tid] = ex;
  }
}

// phase A: scatter edges into bucket-contiguous staging (dense writes).
__launch_bounds__(1024) __global__
void partA_kernel(const int* __restrict__ ei, int* __restrict__ bcursor,
                  int2* __restrict__ staging) {
  __shared__ int lh[NBKT];
  __shared__ int lbase[NBKT];
  const int tid = threadIdx.x;
  for (int i = tid; i < NBKT; i += 1024) lh[i] = 0;
  __syncthreads();
  const int e0 = blockIdx.x * 4096 + tid;
  int s[4], d[4];
#pragma unroll
  for (int k = 0; k < 4; ++k) {
    const int e = e0 + k * 1024;
    const bool ok = e < N_EDGES;
    s[k] = ok ? ei[e] : 0;
    d[k] = ok ? ei[N_EDGES + e] : -1;
    if (ok) atomicAdd(&lh[d[k] >> BKT_SHIFT], 1);
  }
  __syncthreads();
  for (int i = tid; i < NBKT; i += 1024) {
    const int c = lh[i];
    lbase[i] = c ? atomicAdd(&bcursor[i], c) : 0;
    lh[i] = 0;
  }
  __syncthreads();
#pragma unroll
  for (int k = 0; k < 4; ++k) {
    if (d[k] >= 0) {
      const int b = d[k] >> BKT_SHIFT;
      const int p = lbase[b] + atomicAdd(&lh[b], 1);
      staging[p] = make_int2(s[k], d[k]);
    }
  }
}

// phase B: per-bucket local scatter into final CSR (32KB write window).
__launch_bounds__(256) __global__
void partB_kernel(const int2* __restrict__ staging,
                  const int* __restrict__ bbase, const int* __restrict__ bhist,
                  const int* __restrict__ row, int* __restrict__ csr_src) {
  __shared__ int lcur[BKT_NODES];
  const int b = blockIdx.x;
  const int node0 = b << BKT_SHIFT;
  for (int i = threadIdx.x; i < BKT_NODES; i += 256) {
    const int n = node0 + i;
    lcur[i] = (n < N_NODES) ? row[n] : 0;
  }
  __syncthreads();
  const int start = bbase[b];
  const int cnt = bhist[b];
  for (int i = threadIdx.x; i < cnt; i += 256) {
    const int2 e = staging[start + i];
    const int p = atomicAdd(&lcur[e.y - node0], 1);
    csr_src[p] = e.x;
  }
}

// ---------------------------------------------------------------------------
// Layer 1 fused softmax-aggregate. H=2, C=32. One wave per node.
// xl staged in fp16 (128 B/row gather). Scalar src indices; 8 in flight.
// ---------------------------------------------------------------------------
__launch_bounds__(256) __global__
void gat1_kernel(const __half* __restrict__ xlh, const float* __restrict__ xr,
                 const float* __restrict__ att, const int* __restrict__ row,
                 const int* __restrict__ deg, const int* __restrict__ csr_src,
                 float* __restrict__ agg) {
  const int n =
      __builtin_amdgcn_readfirstlane(blockIdx.x * 4 + (threadIdx.x >> 6));
  if (n >= N_NODES) return;
  const int lane = threadIdx.x & 63;
  const int r0 = __builtin_amdgcn_readfirstlane(row[n]);
  const int dg = __builtin_amdgcn_readfirstlane(deg[n]);

  const float xrv = xr[((size_t)n << 6) + lane];
  const float attv = att[lane];

  float s = 0.f, acc = 0.f;
  float xb[8];
#pragma unroll
  for (int k = 0; k < 8; ++k) {
    const int sn = ld_src(csr_src, r0 + k, k, dg);
    xb[k] = __half2float(xlh[((size_t)(unsigned)sn << 6) + lane]);
  }
  for (int j = 0; j < dg; j += 8) {
    float xn[8];
#pragma unroll
    for (int k = 0; k < 8; ++k) {
      const int jj = j + 8 + k;
      const int sn = ld_src(csr_src, r0 + jj, jj, dg);
      xn[k] = __half2float(xlh[((size_t)(unsigned)sn << 6) + lane]);
    }
#pragma unroll
    for (int k = 0; k < 8; ++k) {
      float v = xb[k] + xrv;
      v = fmaxf(v, 0.2f * v);  // leaky_relu
      float p = v * attv;
      p += __shfl_xor(p, 1);
      p += __shfl_xor(p, 2);
      p += __shfl_xor(p, 4);
      p += __shfl_xor(p, 8);
      p += __shfl_xor(p, 16);  // per-head sums
      float e = __expf(p);
      e = (j + k < dg) ? e : 0.f;
      s += e;
      acc = fmaf(e, xb[k], acc);
    }
#pragma unroll
    for (int k = 0; k < 8; ++k) xb[k] = xn[k];
  }
  const float inv = s > 0.f ? 1.f / s : 0.f;
  agg[((size_t)n << 6) + lane] = acc * inv;
}

// ---------------------------------------------------------------------------
// Layer 2 fused: H=1, C=32, fp16 xl (64 B/row gather = 1 line). Two 32-lane
// halves, alternating edges, scalar src indices, 8 in flight.
// Epilogue: bias+relu -> h2, gate scalar inline.
// ---------------------------------------------------------------------------
__launch_bounds__(256) __global__
void gat2_kernel(const __half* __restrict__ xlh, const float* __restrict__ xr,
                 const float* __restrict__ att, const int* __restrict__ row,
                 const int* __restrict__ deg, const int* __restrict__ csr_src,
                 const float* __restrict__ b2, const float* __restrict__ g1w,
                 const float* __restrict__ g1b, const float* __restrict__ g2w,
                 const float* __restrict__ g2b, float* __restrict__ h2,
                 float* __restrict__ gate) {
  const int n =
      __builtin_amdgcn_readfirstlane(blockIdx.x * 4 + (threadIdx.x >> 6));
  if (n >= N_NODES) return;
  const int lane = threadIdx.x & 63;
  const int c = lane & 31;
  const int h = lane >> 5;

  const int r0 = __builtin_amdgcn_readfirstlane(row[n]);
  const int dg = __builtin_amdgcn_readfirstlane(deg[n]);

  const float xrv = xr[(size_t)n * 32 + c];
  const float attv = att[c];

  float s = 0.f, acc = 0.f;
  float xb[4];
#pragma unroll
  for (int k = 0; k < 4; ++k) {
    const int sA = ld_src(csr_src, r0 + 2 * k, 2 * k, dg);
    const int sB = ld_src(csr_src, r0 + 2 * k + 1, 2 * k + 1, dg);
    const int sel = h ? sB : sA;
    xb[k] = __half2float(xlh[((size_t)(unsigned)sel << 5) + c]);
  }
  for (int j = 0; j < dg; j += 8) {
    float xn[4];
#pragma unroll
    for (int k = 0; k < 4; ++k) {
      const int jA = j + 8 + 2 * k;
      const int sA = ld_src(csr_src, r0 + jA, jA, dg);
      const int sB = ld_src(csr_src, r0 + jA + 1, jA + 1, dg);
      const int sel = h ? sB : sA;
      xn[k] = __half2float(xlh[((size_t)(unsigned)sel << 5) + c]);
    }
#pragma unroll
    for (int k = 0; k < 4; ++k) {
      float v = xb[k] + xrv;
      v = fmaxf(v, 0.2f * v);
      float p = v * attv;
      p += __shfl_xor(p, 1);
      p += __shfl_xor(p, 2);
      p += __shfl_xor(p, 4);
      p += __shfl_xor(p, 8);
      p += __shfl_xor(p, 16);
      float e = __expf(p);
      e = (j + 2 * k + h < dg) ? e : 0.f;
      s += e;
      acc = fmaf(e, xb[k], acc);
    }
#pragma unroll
    for (int k = 0; k < 4; ++k) xb[k] = xn[k];
  }
  const float stot = s + __shfl_xor(s, 32);
  const float atot = acc + __shfl_xor(acc, 32);
  const float inv = stot > 0.f ? 1.f / stot : 0.f;
  const float hv = fmaxf(atot * inv + b2[c], 0.f);
  if (h == 0) h2[(size_t)n * 32 + c] = hv;

  float sg = g1b[c];
#pragma unroll
  for (int k = 0; k < 32; ++k)
    sg = fmaf(__shfl(hv, k, 32), g1w[k * 32 + c], sg);
  sg = fmaxf(sg, 0.f);
  float pg = sg * g2w[c];
  pg += __shfl_xor(pg, 1);
  pg += __shfl_xor(pg, 2);
  pg += __shfl_xor(pg, 4);
  pg += __shfl_xor(pg, 8);
  pg += __shfl_xor(pg, 16);
  if (lane == 0) gate[n] = pg + g2b[0];
}

// ---------------------------------------------------------------------------
__launch_bounds__(256) __global__
void gepool_kernel(const float* __restrict__ h2, const int* __restrict__ batch,
                   const float* __restrict__ gate, float* __restrict__ gd,
                   float* __restrict__ pooled) {
  __shared__ float pool[G_GRAPHS * 32];
  __shared__ float gdb[G_GRAPHS];
  const int tid = threadIdx.x;
  for (int i = tid; i < G_GRAPHS * 32; i += 256) pool[i] = 0.f;
  if (tid < G_GRAPHS) gdb[tid] = 0.f;
  __syncthreads();
  const int c = tid & 31;
  const int hw = tid >> 5;
  const int start = blockIdx.x * 256;
  const int end = min(N_NODES, start + 256);
  for (int n = start + hw; n < end; n += 8) {
    const int b = batch[n];
    const float ge = __expf(gate[n]);
    atomicAdd(&pool[b * 32 + c], ge * h2[(size_t)n * 32 + c]);
    if (c == 0) atomicAdd(&gdb[b], ge);
  }
  __syncthreads();
  for (int i = tid; i < G_GRAPHS * 32; i += 256)
    if (pool[i] != 0.f) unsafeAtomicAdd(&pooled[i], pool[i]);
  if (tid < G_GRAPHS && gdb[tid] != 0.f) unsafeAtomicAdd(&gd[tid], gdb[tid]);
}

__launch_bounds__(64) __global__
void final_kernel(const float* __restrict__ pooled, const float* __restrict__ gd,
                  const float* __restrict__ l1w, const float* __restrict__ l1b,
                  const float* __restrict__ l2w, const float* __restrict__ l2b,
                  float* __restrict__ out) {
  const int g = blockIdx.x;
  const int lane = threadIdx.x;
  if (lane >= 32) return;
  const float invgd = 1.f / gd[g];
  float s = l1b[lane];
#pragma unroll
  for (int k = 0; k < 32; ++k)
    s = fmaf(pooled[g * 32 + k] * invgd, l1w[k * 32 + lane], s);
  s = fmaxf(s, 0.f);
  float p = s * l2w[lane];
  p += __shfl_xor(p, 1);
  p += __shfl_xor(p, 2);
  p += __shfl_xor(p, 4);
  p += __shfl_xor(p, 8);
  p += __shfl_xor(p, 16);
  if (lane == 0) out[g] = p + l2b[0];
}

// ---------------------------------------------------------------------------
extern "C" void kernel_launch(void* const* d_in, const int* in_sizes, int n_in,
                              void* d_out, int out_size, void* d_ws,
                              size_t ws_size, hipStream_t stream) {
  const float* x    = (const float*)d_in[0];
  const int*   ei   = (const int*)d_in[1];
  const int*   batch= (const int*)d_in[2];
  const float* Wl1  = (const float*)d_in[3];
  const float* Wr1  = (const float*)d_in[4];
  const float* att1 = (const float*)d_in[5];
  const float* b1   = (const float*)d_in[6];
  const float* Wl2  = (const float*)d_in[7];
  const float* Wr2  = (const float*)d_in[8];
  const float* att2 = (const float*)d_in[9];
  const float* b2   = (const float*)d_in[10];
  const float* g1w  = (const float*)d_in[11];
  const float* g1b  = (const float*)d_in[12];
  const float* g2w  = (const float*)d_in[13];
  const float* g2b  = (const float*)d_in[14];
  const float* l1w  = (const float*)d_in[15];
  const float* l1b  = (const float*)d_in[16];
  const float* l2w  = (const float*)d_in[17];
  const float* l2b  = (const float*)d_in[18];
  float* out = (float*)d_out;

  // ---- workspace layout ----
  int* deg     = (int*)d_ws;            // N        (zeroed)
  int* bhist   = deg + N_NODES;         // NBKT     (zeroed, adjacent)
  int* row     = bhist + NBKT;          // N
  int* bsum    = row + N_NODES;         // SCAN_BLOCKS
  int* boff    = bsum + SCAN_BLOCKS;    // SCAN_BLOCKS
  int* bbase   = boff + SCAN_BLOCKS;    // NBKT
  int* bcursor = bbase + NBKT;          // NBKT
  int* csr_src = bcursor + NBKT;        // E + 16 pad
  int2* staging = (int2*)(csr_src + N_EDGES + 16);  // E int2
  float* fbase = (float*)(staging + N_EDGES);
  float* xr1  = fbase;                         // N*64
  float* agg1 = xr1 + (size_t)N_NODES * 64;    // N*64
  float* gate = agg1 + (size_t)N_NODES * 64;   // N
  float* gd   = gate + N_NODES;                // 64
  float* pooled = gd + G_GRAPHS;               // 64*32
  __half* xl1h = (__half*)(pooled + G_GRAPHS * 32);  // N*64 half
  // layer-2 aliases (safe: stream-ordered producers/consumers)
  __half* xl2h = xl1h;                         // N*32 half
  float* xr2 = xr1;                            // N*32 (first half of xr1)
  float* h2  = xr1 + (size_t)N_NODES * 32;     // N*32 (second half of xr1)

  hipMemsetAsync(deg, 0, (size_t)(N_NODES + NBKT) * sizeof(int), stream);
  hipMemsetAsync(gd, 0, (size_t)(G_GRAPHS + G_GRAPHS * 32) * sizeof(float), stream);

  // CSR build (two-phase partition; shared by both layers)
  hist_kernel<<<(N_EDGES + 1023) / 1024, 256, 0, stream>>>(ei, deg, bhist);
  scan1_kernel<<<SCAN_BLOCKS, 256, 0, stream>>>(deg, bsum);
  scan2_kernel<<<1, 128, 0, stream>>>(bsum, boff);
  scan3_kernel<<<SCAN_BLOCKS, 256, 0, stream>>>(deg, boff, row);
  bscan_kernel<<<1, 256, 0, stream>>>(bhist, bbase, bcursor);
  partA_kernel<<<(N_EDGES + 4095) / 4096, 1024, 0, stream>>>(ei, bcursor,
                                                             staging);
  partB_kernel<<<NBKT, 256, 0, stream>>>(staging, bbase, bhist, row, csr_src);

  // Layer 1 (xl staged fp16)
  gemm_dual<128, 64, false, true><<<(N_NODES + 31) / 32, 256, 0, stream>>>(
      x, Wl1, Wr1, nullptr, (void*)xl1h, xr1, N_NODES);
  gat1_kernel<<<(N_NODES + 3) / 4, 256, 0, stream>>>(xl1h, xr1, att1, row, deg,
                                                     csr_src, agg1);

  // Layer 2 (bias1+relu fused into A-load; gate fused into epilogue)
  gemm_dual<64, 32, true, true><<<(N_NODES + 31) / 32, 256, 0, stream>>>(
      agg1, Wl2, Wr2, b1, (void*)xl2h, xr2, N_NODES);
  gat2_kernel<<<(N_NODES + 3) / 4, 256, 0, stream>>>(
      xl2h, xr2, att2, row, deg, csr_src, b2, g1w, g1b, g2w, g2b, h2, gate);

  // Pooling + head (no-max graph softmax)
  gepool_kernel<<<(N_NODES + 255) / 256, 256, 0, stream>>>(h2, batch, gate, gd,
                                                           pooled);
  final_kernel<<<64, 64, 0, stream>>>(pooled, gd, l1w, l1b, l2w, l2b, out);
}

// Round 10
// 475.093 us; speedup vs baseline: 1.4161x; 1.1571x over previous
//
#include <hip/hip_runtime.h>
#include <hip/hip_fp16.h>
#include <cfloat>
#include <cstdint>
#include <cstddef>

#define N_NODES 100000
#define N_EDGES 1600000
#define G_GRAPHS 64
#define SCAN_CHUNK 1024
#define SCAN_BLOCKS ((N_NODES + SCAN_CHUNK - 1) / SCAN_CHUNK)  // 98
#define BKT_SHIFT 9
#define BKT_NODES (1 << BKT_SHIFT)                              // 512
#define NBKT ((N_NODES + BKT_NODES - 1) >> BKT_SHIFT)           // 196

// Load a (possibly past-end, padded) csr entry, select 0 if beyond dg, and
// force the result into an SGPR.
__device__ __forceinline__ int ld_src(const int* __restrict__ p, int idx,
                                      int i, int lim) {
  int v = p[idx];
  v = (i < lim) ? v : 0;
  return __builtin_amdgcn_readfirstlane(v);
}

// ---------------------------------------------------------------------------
// Dual GEMM, single-pass: O0 = act(A)@W0 (fp16 if HALF0), O1 = act(A)@W1.
// ---------------------------------------------------------------------------
template <int K, int J, bool FUSE, bool HALF0>
__launch_bounds__(256) __global__
void gemm_dual(const float* __restrict__ A, const float* __restrict__ W0,
               const float* __restrict__ W1, const float* __restrict__ bias,
               void* __restrict__ O0v, float* __restrict__ O1, int n) {
  constexpr int BK = 64;
  constexpr int CPT = J / 32;
  __shared__ __align__(16) float As[32][BK];
  __shared__ __align__(16) float W0t[J][BK + 4];
  __shared__ __align__(16) float W1t[J][BK + 4];
  const int tid = threadIdx.x;
  const int n0 = blockIdx.x * 32;
  const int tr = tid >> 5;
  const int tc = tid & 31;

  float acc[4][CPT][2];
#pragma unroll
  for (int i = 0; i < 4; ++i)
#pragma unroll
    for (int j = 0; j < CPT; ++j) {
      acc[i][j][0] = 0.f;
      acc[i][j][1] = 0.f;
    }

  for (int kc = 0; kc < K; kc += BK) {
    for (int i = tid; i < 32 * BK / 4; i += 256) {
      const int node = i / (BK / 4);
      const int kg = i % (BK / 4);
      float4 v = make_float4(0.f, 0.f, 0.f, 0.f);
      if (n0 + node < n) {
        v = reinterpret_cast<const float4*>(
            A)[(size_t)(n0 + node) * (K / 4) + kc / 4 + kg];
        if constexpr (FUSE) {
          const float4 b =
              reinterpret_cast<const float4*>(bias)[kc / 4 + kg];
          v.x = fmaxf(v.x + b.x, 0.f);
          v.y = fmaxf(v.y + b.y, 0.f);
          v.z = fmaxf(v.z + b.z, 0.f);
          v.w = fmaxf(v.w + b.w, 0.f);
        }
      }
      reinterpret_cast<float4*>(&As[node][0])[kg] = v;
    }
    for (int i = tid; i < BK * J; i += 256) {
      const int k = i / J;
      const int j = i % J;
      W0t[j][k] = W0[(size_t)(kc + k) * J + j];
      W1t[j][k] = W1[(size_t)(kc + k) * J + j];
    }
    __syncthreads();

#pragma unroll 2
    for (int k4 = 0; k4 < BK / 4; ++k4) {
      float4 a[4];
#pragma unroll
      for (int i = 0; i < 4; ++i)
        a[i] = reinterpret_cast<const float4*>(&As[tr * 4 + i][0])[k4];
      float4 w0[CPT], w1[CPT];
#pragma unroll
      for (int j = 0; j < CPT; ++j) {
        w0[j] = *reinterpret_cast<const float4*>(&W0t[tc + 32 * j][k4 * 4]);
        w1[j] = *reinterpret_cast<const float4*>(&W1t[tc + 32 * j][k4 * 4]);
      }
#pragma unroll
      for (int i = 0; i < 4; ++i)
#pragma unroll
        for (int j = 0; j < CPT; ++j) {
          acc[i][j][0] = fmaf(a[i].x, w0[j].x, acc[i][j][0]);
          acc[i][j][0] = fmaf(a[i].y, w0[j].y, acc[i][j][0]);
          acc[i][j][0] = fmaf(a[i].z, w0[j].z, acc[i][j][0]);
          acc[i][j][0] = fmaf(a[i].w, w0[j].w, acc[i][j][0]);
          acc[i][j][1] = fmaf(a[i].x, w1[j].x, acc[i][j][1]);
          acc[i][j][1] = fmaf(a[i].y, w1[j].y, acc[i][j][1]);
          acc[i][j][1] = fmaf(a[i].z, w1[j].z, acc[i][j][1]);
          acc[i][j][1] = fmaf(a[i].w, w1[j].w, acc[i][j][1]);
        }
    }
    __syncthreads();
  }

#pragma unroll
  for (int i = 0; i < 4; ++i) {
    const int node = n0 + tr * 4 + i;
    if (node < n) {
      if constexpr (HALF0) {
        __half* O0 = (__half*)O0v;
#pragma unroll
        for (int j = 0; j < CPT; ++j)
          O0[(size_t)node * J + tc + 32 * j] = __float2half(acc[i][j][0]);
      } else {
        float* O0 = (float*)O0v;
#pragma unroll
        for (int j = 0; j < CPT; ++j)
          O0[(size_t)node * J + tc + 32 * j] = acc[i][j][0];
      }
#pragma unroll
      for (int j = 0; j < CPT; ++j)
        O1[(size_t)node * J + tc + 32 * j] = acc[i][j][1];
    }
  }
}

// ---------------------------------------------------------------------------
// CSR build: fused deg+bucket hist -> scans -> two-phase partition.
// ---------------------------------------------------------------------------
__launch_bounds__(256) __global__
void hist_kernel(const int* __restrict__ ei, int* __restrict__ deg,
                 int* __restrict__ bhist) {
  __shared__ int lb[NBKT];
  for (int i = threadIdx.x; i < NBKT; i += 256) lb[i] = 0;
  __syncthreads();
  const int e0 = blockIdx.x * 1024 + threadIdx.x;
#pragma unroll
  for (int k = 0; k < 4; ++k) {
    const int e = e0 + k * 256;
    if (e < N_EDGES) {
      const int dst = ei[N_EDGES + e];
      atomicAdd(&deg[dst], 1);
      atomicAdd(&lb[dst >> BKT_SHIFT], 1);
    }
  }
  __syncthreads();
  for (int i = threadIdx.x; i < NBKT; i += 256)
    if (lb[i]) atomicAdd(&bhist[i], lb[i]);
}

__launch_bounds__(256) __global__
void scan1_kernel(const int* __restrict__ deg, int* __restrict__ bsum) {
  __shared__ int ls[256];
  const int tid = threadIdx.x;
  const int base = blockIdx.x * SCAN_CHUNK + tid * 4;
  int s = 0;
  if (base + 3 < N_NODES) {
    const int4 v = reinterpret_cast<const int4*>(deg)[base >> 2];
    s = v.x + v.y + v.z + v.w;
  } else {
#pragma unroll
    for (int k = 0; k < 4; ++k)
      if (base + k < N_NODES) s += deg[base + k];
  }
  ls[tid] = s;
  __syncthreads();
  for (int d = 128; d > 0; d >>= 1) {
    if (tid < d) ls[tid] += ls[tid + d];
    __syncthreads();
  }
  if (tid == 0) bsum[blockIdx.x] = ls[0];
}

__launch_bounds__(128) __global__
void scan2_kernel(const int* __restrict__ bsum, int* __restrict__ boff) {
  __shared__ int ls[128];
  const int tid = threadIdx.x;
  const int v = (tid < SCAN_BLOCKS) ? bsum[tid] : 0;
  ls[tid] = v;
  __syncthreads();
  for (int d = 1; d < 128; d <<= 1) {
    const int t = (tid >= d) ? ls[tid - d] : 0;
    __syncthreads();
    ls[tid] += t;
    __syncthreads();
  }
  if (tid < SCAN_BLOCKS) boff[tid] = ls[tid] - v;
}

__launch_bounds__(256) __global__
void scan3_kernel(const int* __restrict__ deg, const int* __restrict__ boff,
                  int* __restrict__ row) {
  __shared__ int ls[256];
  const int tid = threadIdx.x;
  const int base = blockIdx.x * SCAN_CHUNK + tid * 4;
  int4 v = make_int4(0, 0, 0, 0);
  if (base + 3 < N_NODES) {
    v = reinterpret_cast<const int4*>(deg)[base >> 2];
  } else {
    if (base + 0 < N_NODES) v.x = deg[base + 0];
    if (base + 1 < N_NODES) v.y = deg[base + 1];
    if (base + 2 < N_NODES) v.z = deg[base + 2];
    if (base + 3 < N_NODES) v.w = deg[base + 3];
  }
  const int s = v.x + v.y + v.z + v.w;
  ls[tid] = s;
  __syncthreads();
  for (int d = 1; d < 256; d <<= 1) {
    const int t = (tid >= d) ? ls[tid - d] : 0;
    __syncthreads();
    ls[tid] += t;
    __syncthreads();
  }
  const int run = ls[tid] - s + boff[blockIdx.x];
  const int4 r = make_int4(run, run + v.x, run + v.x + v.y,
                           run + v.x + v.y + v.z);
  if (base + 3 < N_NODES) {
    reinterpret_cast<int4*>(row)[base >> 2] = r;
  } else {
    if (base + 0 < N_NODES) row[base + 0] = r.x;
    if (base + 1 < N_NODES) row[base + 1] = r.y;
    if (base + 2 < N_NODES) row[base + 2] = r.z;
    if (base + 3 < N_NODES) row[base + 3] = r.w;
  }
}

__launch_bounds__(256) __global__
void bscan_kernel(const int* __restrict__ bhist, int* __restrict__ bbase,
                  int* __restrict__ bcursor) {
  __shared__ int ls[256];
  const int tid = threadIdx.x;
  const int v = (tid < NBKT) ? bhist[tid] : 0;
  ls[tid] = v;
  __syncthreads();
  for (int d = 1; d < 256; d <<= 1) {
    const int t = (tid >= d) ? ls[tid - d] : 0;
    __syncthreads();
    ls[tid] += t;
    __syncthreads();
  }
  if (tid < NBKT) {
    const int ex = ls[tid] - v;
    bbase[tid] = ex;
    bcursor[tid] = ex;
  }
}

__launch_bounds__(1024) __global__
void partA_kernel(const int* __restrict__ ei, int* __restrict__ bcursor,
                  int2* __restrict__ staging) {
  __shared__ int lh[NBKT];
  __shared__ int lbase[NBKT];
  const int tid = threadIdx.x;
  for (int i = tid; i < NBKT; i += 1024) lh[i] = 0;
  __syncthreads();
  const int e0 = blockIdx.x * 4096 + tid;
  int s[4], d[4];
#pragma unroll
  for (int k = 0; k < 4; ++k) {
    const int e = e0 + k * 1024;
    const bool ok = e < N_EDGES;
    s[k] = ok ? ei[e] : 0;
    d[k] = ok ? ei[N_EDGES + e] : -1;
    if (ok) atomicAdd(&lh[d[k] >> BKT_SHIFT], 1);
  }
  __syncthreads();
  for (int i = tid; i < NBKT; i += 1024) {
    const int c = lh[i];
    lbase[i] = c ? atomicAdd(&bcursor[i], c) : 0;
    lh[i] = 0;
  }
  __syncthreads();
#pragma unroll
  for (int k = 0; k < 4; ++k) {
    if (d[k] >= 0) {
      const int b = d[k] >> BKT_SHIFT;
      const int p = lbase[b] + atomicAdd(&lh[b], 1);
      staging[p] = make_int2(s[k], d[k]);
    }
  }
}

__launch_bounds__(256) __global__
void partB_kernel(const int2* __restrict__ staging,
                  const int* __restrict__ bbase, const int* __restrict__ bhist,
                  const int* __restrict__ row, int* __restrict__ csr_src) {
  __shared__ int lcur[BKT_NODES];
  const int b = blockIdx.x;
  const int node0 = b << BKT_SHIFT;
  for (int i = threadIdx.x; i < BKT_NODES; i += 256) {
    const int n = node0 + i;
    lcur[i] = (n < N_NODES) ? row[n] : 0;
  }
  __syncthreads();
  const int start = bbase[b];
  const int cnt = bhist[b];
  for (int i = threadIdx.x; i < cnt; i += 256) {
    const int2 e = staging[start + i];
    const int p = atomicAdd(&lcur[e.y - node0], 1);
    csr_src[p] = e.x;
  }
}

// ---------------------------------------------------------------------------
// Layer 1 fused softmax-aggregate. H=2, C=32. One wave per node; the two
// 32-lane halves process 2 edges simultaneously, each lane holding a
// channel PAIR (fp16x2 gather). Head = 16-lane group; 4-level xor reduce.
// ---------------------------------------------------------------------------
__launch_bounds__(256) __global__
void gat1_kernel(const __half* __restrict__ xlh, const float* __restrict__ xr,
                 const float* __restrict__ att, const int* __restrict__ row,
                 const int* __restrict__ deg, const int* __restrict__ csr_src,
                 float* __restrict__ agg) {
  const int n =
      __builtin_amdgcn_readfirstlane(blockIdx.x * 4 + (threadIdx.x >> 6));
  if (n >= N_NODES) return;
  const int lane = threadIdx.x & 63;
  const int half = lane >> 5;  // edge slot (A/B)
  const int l = lane & 31;     // channel-pair index: channels 2l, 2l+1
  const int r0 = __builtin_amdgcn_readfirstlane(row[n]);
  const int dg = __builtin_amdgcn_readfirstlane(deg[n]);

  const float2 xrv =
      *reinterpret_cast<const float2*>(xr + ((size_t)n << 6) + 2 * l);
  const float2 attv = *reinterpret_cast<const float2*>(att + 2 * l);

  float s = 0.f;
  float2 acc = make_float2(0.f, 0.f);
  const int T = (dg + 1) >> 1;  // edge pairs

  __half2 xb[4];
#pragma unroll
  for (int k = 0; k < 4; ++k) {
    const int sA = ld_src(csr_src, r0 + 2 * k, 2 * k, dg);
    const int sB = ld_src(csr_src, r0 + 2 * k + 1, 2 * k + 1, dg);
    const int sel = half ? sB : sA;
    xb[k] = *reinterpret_cast<const __half2*>(
        (const char*)xlh + (((size_t)(unsigned)sel) << 7) + 4 * l);
  }
  for (int t = 0; t < T; t += 4) {
    __half2 xn[4];
#pragma unroll
    for (int k = 0; k < 4; ++k) {
      const int tp = t + 4 + k;
      const int sA = ld_src(csr_src, r0 + 2 * tp, 2 * tp, dg);
      const int sB = ld_src(csr_src, r0 + 2 * tp + 1, 2 * tp + 1, dg);
      const int sel = half ? sB : sA;
      xn[k] = *reinterpret_cast<const __half2*>(
          (const char*)xlh + (((size_t)(unsigned)sel) << 7) + 4 * l);
    }
#pragma unroll
    for (int k = 0; k < 4; ++k) {
      const float2 a = __half22float2(xb[k]);
      float vx = a.x + xrv.x, vy = a.y + xrv.y;
      vx = fmaxf(vx, 0.2f * vx);
      vy = fmaxf(vy, 0.2f * vy);
      float p = fmaf(vy, attv.y, vx * attv.x);
      p += __shfl_xor(p, 1);
      p += __shfl_xor(p, 2);
      p += __shfl_xor(p, 4);
      p += __shfl_xor(p, 8);  // 16-lane head-group sum (butterfly: all lanes)
      float e = __expf(p);
      e = (2 * (t + k) + half < dg) ? e : 0.f;
      s += e;
      acc.x = fmaf(e, a.x, acc.x);
      acc.y = fmaf(e, a.y, acc.y);
    }
#pragma unroll
    for (int k = 0; k < 4; ++k) xb[k] = xn[k];
  }
  // merge the two edge slots
  s += __shfl_xor(s, 32);
  acc.x += __shfl_xor(acc.x, 32);
  acc.y += __shfl_xor(acc.y, 32);
  const float inv = s > 0.f ? 1.f / s : 0.f;
  if (half == 0)
    *reinterpret_cast<float2*>(agg + ((size_t)n << 6) + 2 * l) =
        make_float2(acc.x * inv, acc.y * inv);
}

// ---------------------------------------------------------------------------
// Layer 2 fused: H=1, C=32. Four 16-lane groups process 4 edges at once,
// each lane holds a channel pair. Butterfly merges leave all lanes with the
// full result. Epilogue: bias+relu -> h2, gate scalar inline.
// ---------------------------------------------------------------------------
__launch_bounds__(256) __global__
void gat2_kernel(const __half* __restrict__ xlh, const float* __restrict__ xr,
                 const float* __restrict__ att, const int* __restrict__ row,
                 const int* __restrict__ deg, const int* __restrict__ csr_src,
                 const float* __restrict__ b2, const float* __restrict__ g1w,
                 const float* __restrict__ g1b, const float* __restrict__ g2w,
                 const float* __restrict__ g2b, float* __restrict__ h2,
                 float* __restrict__ gate) {
  const int n =
      __builtin_amdgcn_readfirstlane(blockIdx.x * 4 + (threadIdx.x >> 6));
  if (n >= N_NODES) return;
  const int lane = threadIdx.x & 63;
  const int g = lane >> 4;   // edge group 0..3
  const int m = lane & 15;   // channel-pair index: channels 2m, 2m+1

  const int r0 = __builtin_amdgcn_readfirstlane(row[n]);
  const int dg = __builtin_amdgcn_readfirstlane(deg[n]);

  const float2 xrv =
      *reinterpret_cast<const float2*>(xr + (size_t)n * 32 + 2 * m);
  const float2 attv = *reinterpret_cast<const float2*>(att + 2 * m);

  float s = 0.f;
  float2 acc = make_float2(0.f, 0.f);
  const int Q = (dg + 3) >> 2;  // edge quads

  __half2 xb[2];
#pragma unroll
  for (int k = 0; k < 2; ++k) {
    const int s0 = ld_src(csr_src, r0 + 4 * k + 0, 4 * k + 0, dg);
    const int s1 = ld_src(csr_src, r0 + 4 * k + 1, 4 * k + 1, dg);
    const int s2 = ld_src(csr_src, r0 + 4 * k + 2, 4 * k + 2, dg);
    const int s3 = ld_src(csr_src, r0 + 4 * k + 3, 4 * k + 3, dg);
    const int selLo = (g & 1) ? s1 : s0;
    const int selHi = (g & 1) ? s3 : s2;
    const int sel = (g & 2) ? selHi : selLo;
    xb[k] = *reinterpret_cast<const __half2*>(
        (const char*)xlh + (((size_t)(unsigned)sel) << 6) + 4 * m);
  }
  for (int t = 0; t < Q; t += 2) {
    __half2 xn[2];
#pragma unroll
    for (int k = 0; k < 2; ++k) {
      const int q = t + 2 + k;
      const int s0 = ld_src(csr_src, r0 + 4 * q + 0, 4 * q + 0, dg);
      const int s1 = ld_src(csr_src, r0 + 4 * q + 1, 4 * q + 1, dg);
      const int s2 = ld_src(csr_src, r0 + 4 * q + 2, 4 * q + 2, dg);
      const int s3 = ld_src(csr_src, r0 + 4 * q + 3, 4 * q + 3, dg);
      const int selLo = (g & 1) ? s1 : s0;
      const int selHi = (g & 1) ? s3 : s2;
      const int sel = (g & 2) ? selHi : selLo;
      xn[k] = *reinterpret_cast<const __half2*>(
          (const char*)xlh + (((size_t)(unsigned)sel) << 6) + 4 * m);
    }
#pragma unroll
    for (int k = 0; k < 2; ++k) {
      const float2 a = __half22float2(xb[k]);
      float vx = a.x + xrv.x, vy = a.y + xrv.y;
      vx = fmaxf(vx, 0.2f * vx);
      vy = fmaxf(vy, 0.2f * vy);
      float p = fmaf(vy, attv.y, vx * attv.x);
      p += __shfl_xor(p, 1);
      p += __shfl_xor(p, 2);
      p += __shfl_xor(p, 4);
      p += __shfl_xor(p, 8);  // 16-lane (edge) sum
      float e = __expf(p);
      e = (4 * (t + k) + g < dg) ? e : 0.f;
      s += e;
      acc.x = fmaf(e, a.x, acc.x);
      acc.y = fmaf(e, a.y, acc.y);
    }
#pragma unroll
    for (int k = 0; k < 2; ++k) xb[k] = xn[k];
  }
  // merge the 4 edge groups (butterfly: all lanes get totals)
  s += __shfl_xor(s, 16);
  s += __shfl_xor(s, 32);
  acc.x += __shfl_xor(acc.x, 16);
  acc.x += __shfl_xor(acc.x, 32);
  acc.y += __shfl_xor(acc.y, 16);
  acc.y += __shfl_xor(acc.y, 32);
  const float inv = s > 0.f ? 1.f / s : 0.f;
  const float2 b2v = *reinterpret_cast<const float2*>(b2 + 2 * m);
  const float2 hv2 = make_float2(fmaxf(acc.x * inv + b2v.x, 0.f),
                                 fmaxf(acc.y * inv + b2v.y, 0.f));
  if (g == 0)
    *reinterpret_cast<float2*>(h2 + (size_t)n * 32 + 2 * m) = hv2;

  // redistribute to 1-channel-per-lane layout for the gate matvec
  const int c = lane & 31;
  const float hx = __shfl(hv2.x, c >> 1, 32);
  const float hy = __shfl(hv2.y, c >> 1, 32);
  const float hv = (c & 1) ? hy : hx;
  float sg = g1b[c];
#pragma unroll
  for (int k = 0; k < 32; ++k)
    sg = fmaf(__shfl(hv, k, 32), g1w[k * 32 + c], sg);
  sg = fmaxf(sg, 0.f);
  float pg = sg * g2w[c];
  pg += __shfl_xor(pg, 1);
  pg += __shfl_xor(pg, 2);
  pg += __shfl_xor(pg, 4);
  pg += __shfl_xor(pg, 8);
  pg += __shfl_xor(pg, 16);
  if (lane == 0) gate[n] = pg + g2b[0];
}

// ---------------------------------------------------------------------------
__launch_bounds__(256) __global__
void gepool_kernel(const float* __restrict__ h2, const int* __restrict__ batch,
                   const float* __restrict__ gate, float* __restrict__ gd,
                   float* __restrict__ pooled) {
  __shared__ float pool[G_GRAPHS * 32];
  __shared__ float gdb[G_GRAPHS];
  const int tid = threadIdx.x;
  for (int i = tid; i < G_GRAPHS * 32; i += 256) pool[i] = 0.f;
  if (tid < G_GRAPHS) gdb[tid] = 0.f;
  __syncthreads();
  const int c = tid & 31;
  const int hw = tid >> 5;
  const int start = blockIdx.x * 256;
  const int end = min(N_NODES, start + 256);
  for (int n = start + hw; n < end; n += 8) {
    const int b = batch[n];
    const float ge = __expf(gate[n]);
    atomicAdd(&pool[b * 32 + c], ge * h2[(size_t)n * 32 + c]);
    if (c == 0) atomicAdd(&gdb[b], ge);
  }
  __syncthreads();
  for (int i = tid; i < G_GRAPHS * 32; i += 256)
    if (pool[i] != 0.f) unsafeAtomicAdd(&pooled[i], pool[i]);
  if (tid < G_GRAPHS && gdb[tid] != 0.f) unsafeAtomicAdd(&gd[tid], gdb[tid]);
}

__launch_bounds__(64) __global__
void final_kernel(const float* __restrict__ pooled, const float* __restrict__ gd,
                  const float* __restrict__ l1w, const float* __restrict__ l1b,
                  const float* __restrict__ l2w, const float* __restrict__ l2b,
                  float* __restrict__ out) {
  const int g = blockIdx.x;
  const int lane = threadIdx.x;
  if (lane >= 32) return;
  const float invgd = 1.f / gd[g];
  float s = l1b[lane];
#pragma unroll
  for (int k = 0; k < 32; ++k)
    s = fmaf(pooled[g * 32 + k] * invgd, l1w[k * 32 + lane], s);
  s = fmaxf(s, 0.f);
  float p = s * l2w[lane];
  p += __shfl_xor(p, 1);
  p += __shfl_xor(p, 2);
  p += __shfl_xor(p, 4);
  p += __shfl_xor(p, 8);
  p += __shfl_xor(p, 16);
  if (lane == 0) out[g] = p + l2b[0];
}

// ---------------------------------------------------------------------------
extern "C" void kernel_launch(void* const* d_in, const int* in_sizes, int n_in,
                              void* d_out, int out_size, void* d_ws,
                              size_t ws_size, hipStream_t stream) {
  const float* x    = (const float*)d_in[0];
  const int*   ei   = (const int*)d_in[1];
  const int*   batch= (const int*)d_in[2];
  const float* Wl1  = (const float*)d_in[3];
  const float* Wr1  = (const float*)d_in[4];
  const float* att1 = (const float*)d_in[5];
  const float* b1   = (const float*)d_in[6];
  const float* Wl2  = (const float*)d_in[7];
  const float* Wr2  = (const float*)d_in[8];
  const float* att2 = (const float*)d_in[9];
  const float* b2   = (const float*)d_in[10];
  const float* g1w  = (const float*)d_in[11];
  const float* g1b  = (const float*)d_in[12];
  const float* g2w  = (const float*)d_in[13];
  const float* g2b  = (const float*)d_in[14];
  const float* l1w  = (const float*)d_in[15];
  const float* l1b  = (const float*)d_in[16];
  const float* l2w  = (const float*)d_in[17];
  const float* l2b  = (const float*)d_in[18];
  float* out = (float*)d_out;

  // ---- workspace layout ----
  int* deg     = (int*)d_ws;            // N        (zeroed)
  int* bhist   = deg + N_NODES;         // NBKT     (zeroed, adjacent)
  int* row     = bhist + NBKT;          // N
  int* bsum    = row + N_NODES;         // SCAN_BLOCKS
  int* boff    = bsum + SCAN_BLOCKS;    // SCAN_BLOCKS
  int* bbase   = boff + SCAN_BLOCKS;    // NBKT
  int* bcursor = bbase + NBKT;          // NBKT
  int* csr_src = bcursor + NBKT;        // E + 16 pad
  int2* staging = (int2*)(csr_src + N_EDGES + 16);  // E int2
  float* fbase = (float*)(staging + N_EDGES);
  float* xr1  = fbase;                         // N*64
  float* agg1 = xr1 + (size_t)N_NODES * 64;    // N*64
  float* gate = agg1 + (size_t)N_NODES * 64;   // N
  float* gd   = gate + N_NODES;                // 64
  float* pooled = gd + G_GRAPHS;               // 64*32
  __half* xl1h = (__half*)(pooled + G_GRAPHS * 32);  // N*64 half
  // layer-2 aliases (stream-ordered producers/consumers)
  __half* xl2h = xl1h;                         // N*32 half
  float* xr2 = xr1;                            // N*32 (first half of xr1)
  float* h2  = xr1 + (size_t)N_NODES * 32;     // N*32 (second half of xr1)

  hipMemsetAsync(deg, 0, (size_t)(N_NODES + NBKT) * sizeof(int), stream);
  hipMemsetAsync(gd, 0, (size_t)(G_GRAPHS + G_GRAPHS * 32) * sizeof(float), stream);

  // CSR build (two-phase partition; shared by both layers)
  hist_kernel<<<(N_EDGES + 1023) / 1024, 256, 0, stream>>>(ei, deg, bhist);
  scan1_kernel<<<SCAN_BLOCKS, 256, 0, stream>>>(deg, bsum);
  scan2_kernel<<<1, 128, 0, stream>>>(bsum, boff);
  scan3_kernel<<<SCAN_BLOCKS, 256, 0, stream>>>(deg, boff, row);
  bscan_kernel<<<1, 256, 0, stream>>>(bhist, bbase, bcursor);
  partA_kernel<<<(N_EDGES + 4095) / 4096, 1024, 0, stream>>>(ei, bcursor,
                                                             staging);
  partB_kernel<<<NBKT, 256, 0, stream>>>(staging, bbase, bhist, row, csr_src);

  // Layer 1 (xl staged fp16)
  gemm_dual<128, 64, false, true><<<(N_NODES + 31) / 32, 256, 0, stream>>>(
      x, Wl1, Wr1, nullptr, (void*)xl1h, xr1, N_NODES);
  gat1_kernel<<<(N_NODES + 3) / 4, 256, 0, stream>>>(xl1h, xr1, att1, row, deg,
                                                     csr_src, agg1);

  // Layer 2 (bias1+relu fused into A-load; gate fused into epilogue)
  gemm_dual<64, 32, true, true><<<(N_NODES + 31) / 32, 256, 0, stream>>>(
      agg1, Wl2, Wr2, b1, (void*)xl2h, xr2, N_NODES);
  gat2_kernel<<<(N_NODES + 3) / 4, 256, 0, stream>>>(
      xl2h, xr2, att2, row, deg, csr_src, b2, g1w, g1b, g2w, g2b, h2, gate);

  // Pooling + head (no-max graph softmax)
  gepool_kernel<<<(N_NODES + 255) / 256, 256, 0, stream>>>(h2, batch, gate, gd,
                                                           pooled);
  final_kernel<<<64, 64, 0, stream>>>(pooled, gd, l1w, l1b, l2w, l2b, out);
}

// Round 11
// 425.195 us; speedup vs baseline: 1.5823x; 1.1174x over previous
//
#include <hip/hip_runtime.h>
#include <hip/hip_fp16.h>
#include <cfloat>
#include <cstdint>
#include <cstddef>

#define N_NODES 100000
#define N_EDGES 1600000
#define G_GRAPHS 64
#define BKT_SHIFT 9
#define BKT_NODES (1 << BKT_SHIFT)                              // 512
#define NBKT ((N_NODES + BKT_NODES - 1) >> BKT_SHIFT)           // 196

// Load a (possibly past-end, padded) csr entry, select 0 if beyond dg, and
// force the result into an SGPR.
__device__ __forceinline__ int ld_src(const int* __restrict__ p, int idx,
                                      int i, int lim) {
  int v = p[idx];
  v = (i < lim) ? v : 0;
  return __builtin_amdgcn_readfirstlane(v);
}

// ---------------------------------------------------------------------------
// Dual GEMM, single-pass: O0 = act(A)@W0 (fp16 if HALF0), O1 = act(A)@W1.
// ---------------------------------------------------------------------------
template <int K, int J, bool FUSE, bool HALF0>
__launch_bounds__(256) __global__
void gemm_dual(const float* __restrict__ A, const float* __restrict__ W0,
               const float* __restrict__ W1, const float* __restrict__ bias,
               void* __restrict__ O0v, float* __restrict__ O1, int n) {
  constexpr int BK = 64;
  constexpr int CPT = J / 32;
  __shared__ __align__(16) float As[32][BK];
  __shared__ __align__(16) float W0t[J][BK + 4];
  __shared__ __align__(16) float W1t[J][BK + 4];
  const int tid = threadIdx.x;
  const int n0 = blockIdx.x * 32;
  const int tr = tid >> 5;
  const int tc = tid & 31;

  float acc[4][CPT][2];
#pragma unroll
  for (int i = 0; i < 4; ++i)
#pragma unroll
    for (int j = 0; j < CPT; ++j) {
      acc[i][j][0] = 0.f;
      acc[i][j][1] = 0.f;
    }

  for (int kc = 0; kc < K; kc += BK) {
    for (int i = tid; i < 32 * BK / 4; i += 256) {
      const int node = i / (BK / 4);
      const int kg = i % (BK / 4);
      float4 v = make_float4(0.f, 0.f, 0.f, 0.f);
      if (n0 + node < n) {
        v = reinterpret_cast<const float4*>(
            A)[(size_t)(n0 + node) * (K / 4) + kc / 4 + kg];
        if constexpr (FUSE) {
          const float4 b =
              reinterpret_cast<const float4*>(bias)[kc / 4 + kg];
          v.x = fmaxf(v.x + b.x, 0.f);
          v.y = fmaxf(v.y + b.y, 0.f);
          v.z = fmaxf(v.z + b.z, 0.f);
          v.w = fmaxf(v.w + b.w, 0.f);
        }
      }
      reinterpret_cast<float4*>(&As[node][0])[kg] = v;
    }
    for (int i = tid; i < BK * J; i += 256) {
      const int k = i / J;
      const int j = i % J;
      W0t[j][k] = W0[(size_t)(kc + k) * J + j];
      W1t[j][k] = W1[(size_t)(kc + k) * J + j];
    }
    __syncthreads();

#pragma unroll 2
    for (int k4 = 0; k4 < BK / 4; ++k4) {
      float4 a[4];
#pragma unroll
      for (int i = 0; i < 4; ++i)
        a[i] = reinterpret_cast<const float4*>(&As[tr * 4 + i][0])[k4];
      float4 w0[CPT], w1[CPT];
#pragma unroll
      for (int j = 0; j < CPT; ++j) {
        w0[j] = *reinterpret_cast<const float4*>(&W0t[tc + 32 * j][k4 * 4]);
        w1[j] = *reinterpret_cast<const float4*>(&W1t[tc + 32 * j][k4 * 4]);
      }
#pragma unroll
      for (int i = 0; i < 4; ++i)
#pragma unroll
        for (int j = 0; j < CPT; ++j) {
          acc[i][j][0] = fmaf(a[i].x, w0[j].x, acc[i][j][0]);
          acc[i][j][0] = fmaf(a[i].y, w0[j].y, acc[i][j][0]);
          acc[i][j][0] = fmaf(a[i].z, w0[j].z, acc[i][j][0]);
          acc[i][j][0] = fmaf(a[i].w, w0[j].w, acc[i][j][0]);
          acc[i][j][1] = fmaf(a[i].x, w1[j].x, acc[i][j][1]);
          acc[i][j][1] = fmaf(a[i].y, w1[j].y, acc[i][j][1]);
          acc[i][j][1] = fmaf(a[i].z, w1[j].z, acc[i][j][1]);
          acc[i][j][1] = fmaf(a[i].w, w1[j].w, acc[i][j][1]);
        }
    }
    __syncthreads();
  }

#pragma unroll
  for (int i = 0; i < 4; ++i) {
    const int node = n0 + tr * 4 + i;
    if (node < n) {
      if constexpr (HALF0) {
        __half* O0 = (__half*)O0v;
#pragma unroll
        for (int j = 0; j < CPT; ++j)
          O0[(size_t)node * J + tc + 32 * j] = __float2half(acc[i][j][0]);
      } else {
        float* O0 = (float*)O0v;
#pragma unroll
        for (int j = 0; j < CPT; ++j)
          O0[(size_t)node * J + tc + 32 * j] = acc[i][j][0];
      }
#pragma unroll
      for (int j = 0; j < CPT; ++j)
        O1[(size_t)node * J + tc + 32 * j] = acc[i][j][1];
    }
  }
}

// ---------------------------------------------------------------------------
// CSR build: bucket hist (LDS only) -> bucket scan -> partition ->
// per-bucket deg/row/scatter (all per-node RMW in LDS).
// ---------------------------------------------------------------------------
__launch_bounds__(256) __global__
void histB_kernel(const int* __restrict__ ei, int* __restrict__ bhist) {
  __shared__ int lb[NBKT];
  for (int i = threadIdx.x; i < NBKT; i += 256) lb[i] = 0;
  __syncthreads();
  const int e0 = blockIdx.x * 1024 + threadIdx.x;
#pragma unroll
  for (int k = 0; k < 4; ++k) {
    const int e = e0 + k * 256;
    if (e < N_EDGES) atomicAdd(&lb[ei[N_EDGES + e] >> BKT_SHIFT], 1);
  }
  __syncthreads();
  for (int i = threadIdx.x; i < NBKT; i += 256)
    if (lb[i]) atomicAdd(&bhist[i], lb[i]);
}

__launch_bounds__(256) __global__
void bscan_kernel(const int* __restrict__ bhist, int* __restrict__ bbase,
                  int* __restrict__ bcursor) {
  __shared__ int ls[256];
  const int tid = threadIdx.x;
  const int v = (tid < NBKT) ? bhist[tid] : 0;
  ls[tid] = v;
  __syncthreads();
  for (int d = 1; d < 256; d <<= 1) {
    const int t = (tid >= d) ? ls[tid - d] : 0;
    __syncthreads();
    ls[tid] += t;
    __syncthreads();
  }
  if (tid < NBKT) {
    const int ex = ls[tid] - v;
    bbase[tid] = ex;
    bcursor[tid] = ex;
  }
}

// phase A: scatter edges into bucket-contiguous staging (dense writes).
__launch_bounds__(1024) __global__
void partA_kernel(const int* __restrict__ ei, int* __restrict__ bcursor,
                  int2* __restrict__ staging) {
  __shared__ int lh[NBKT];
  __shared__ int lbase[NBKT];
  const int tid = threadIdx.x;
  for (int i = tid; i < NBKT; i += 1024) lh[i] = 0;
  __syncthreads();
  const int e0 = blockIdx.x * 4096 + tid;
  int s[4], d[4];
#pragma unroll
  for (int k = 0; k < 4; ++k) {
    const int e = e0 + k * 1024;
    const bool ok = e < N_EDGES;
    s[k] = ok ? ei[e] : 0;
    d[k] = ok ? ei[N_EDGES + e] : -1;
    if (ok) atomicAdd(&lh[d[k] >> BKT_SHIFT], 1);
  }
  __syncthreads();
  for (int i = tid; i < NBKT; i += 1024) {
    const int c = lh[i];
    lbase[i] = c ? atomicAdd(&bcursor[i], c) : 0;
    lh[i] = 0;
  }
  __syncthreads();
#pragma unroll
  for (int k = 0; k < 4; ++k) {
    if (d[k] >= 0) {
      const int b = d[k] >> BKT_SHIFT;
      const int p = lbase[b] + atomicAdd(&lh[b], 1);
      staging[p] = make_int2(s[k], d[k]);
    }
  }
}

// phase B: per-bucket deg count (LDS), 512-scan -> row, then local scatter.
__launch_bounds__(256) __global__
void partB_kernel(const int2* __restrict__ staging,
                  const int* __restrict__ bbase, const int* __restrict__ bhist,
                  int* __restrict__ deg, int* __restrict__ row,
                  int* __restrict__ csr_src) {
  __shared__ int ldeg[BKT_NODES];
  __shared__ int lsc[256];
  const int b = blockIdx.x;
  const int tid = threadIdx.x;
  const int node0 = b << BKT_SHIFT;
  ldeg[2 * tid] = 0;
  ldeg[2 * tid + 1] = 0;
  __syncthreads();
  const int start = bbase[b];
  const int cnt = bhist[b];
  for (int i = tid; i < cnt; i += 256)
    atomicAdd(&ldeg[staging[start + i].y - node0], 1);
  __syncthreads();
  // 512-wide exclusive scan (2 elems/thread)
  const int d0 = ldeg[2 * tid];
  const int d1 = ldeg[2 * tid + 1];
  const int psum = d0 + d1;
  lsc[tid] = psum;
  __syncthreads();
  for (int d = 1; d < 256; d <<= 1) {
    const int t = (tid >= d) ? lsc[tid - d] : 0;
    __syncthreads();
    lsc[tid] += t;
    __syncthreads();
  }
  const int ex = lsc[tid] - psum + start;  // global CSR offset
  const int n0 = node0 + 2 * tid;
  if (n0 < N_NODES) {
    deg[n0] = d0;
    row[n0] = ex;
  }
  if (n0 + 1 < N_NODES) {
    deg[n0 + 1] = d1;
    row[n0 + 1] = ex + d0;
  }
  __syncthreads();
  // reuse ldeg as write cursor
  ldeg[2 * tid] = ex;
  ldeg[2 * tid + 1] = ex + d0;
  __syncthreads();
  for (int i = tid; i < cnt; i += 256) {
    const int2 e = staging[start + i];
    const int p = atomicAdd(&ldeg[e.y - node0], 1);
    csr_src[p] = e.x;
  }
}

// ---------------------------------------------------------------------------
// Layer 1 fused softmax-aggregate. H=2, C=32. One wave per node; the two
// 32-lane halves process 2 edges simultaneously, each lane holding a
// channel PAIR (fp16x2 gather). Head = 16-lane group; 4-level xor reduce.
// ---------------------------------------------------------------------------
__launch_bounds__(256) __global__
void gat1_kernel(const __half* __restrict__ xlh, const float* __restrict__ xr,
                 const float* __restrict__ att, const int* __restrict__ row,
                 const int* __restrict__ deg, const int* __restrict__ csr_src,
                 float* __restrict__ agg) {
  const int n =
      __builtin_amdgcn_readfirstlane(blockIdx.x * 4 + (threadIdx.x >> 6));
  if (n >= N_NODES) return;
  const int lane = threadIdx.x & 63;
  const int half = lane >> 5;  // edge slot (A/B)
  const int l = lane & 31;     // channel-pair index: channels 2l, 2l+1
  const int r0 = __builtin_amdgcn_readfirstlane(row[n]);
  const int dg = __builtin_amdgcn_readfirstlane(deg[n]);

  const float2 xrv =
      *reinterpret_cast<const float2*>(xr + ((size_t)n << 6) + 2 * l);
  const float2 attv = *reinterpret_cast<const float2*>(att + 2 * l);

  float s = 0.f;
  float2 acc = make_float2(0.f, 0.f);
  const int T = (dg + 1) >> 1;  // edge pairs

  __half2 xb[4];
#pragma unroll
  for (int k = 0; k < 4; ++k) {
    const int sA = ld_src(csr_src, r0 + 2 * k, 2 * k, dg);
    const int sB = ld_src(csr_src, r0 + 2 * k + 1, 2 * k + 1, dg);
    const int sel = half ? sB : sA;
    xb[k] = *reinterpret_cast<const __half2*>(
        (const char*)xlh + (((size_t)(unsigned)sel) << 7) + 4 * l);
  }
  for (int t = 0; t < T; t += 4) {
    __half2 xn[4];
#pragma unroll
    for (int k = 0; k < 4; ++k) {
      const int tp = t + 4 + k;
      const int sA = ld_src(csr_src, r0 + 2 * tp, 2 * tp, dg);
      const int sB = ld_src(csr_src, r0 + 2 * tp + 1, 2 * tp + 1, dg);
      const int sel = half ? sB : sA;
      xn[k] = *reinterpret_cast<const __half2*>(
          (const char*)xlh + (((size_t)(unsigned)sel) << 7) + 4 * l);
    }
#pragma unroll
    for (int k = 0; k < 4; ++k) {
      const float2 a = __half22float2(xb[k]);
      float vx = a.x + xrv.x, vy = a.y + xrv.y;
      vx = fmaxf(vx, 0.2f * vx);
      vy = fmaxf(vy, 0.2f * vy);
      float p = fmaf(vy, attv.y, vx * attv.x);
      p += __shfl_xor(p, 1);
      p += __shfl_xor(p, 2);
      p += __shfl_xor(p, 4);
      p += __shfl_xor(p, 8);  // 16-lane head-group sum (butterfly: all lanes)
      float e = __expf(p);
      e = (2 * (t + k) + half < dg) ? e : 0.f;
      s += e;
      acc.x = fmaf(e, a.x, acc.x);
      acc.y = fmaf(e, a.y, acc.y);
    }
#pragma unroll
    for (int k = 0; k < 4; ++k) xb[k] = xn[k];
  }
  // merge the two edge slots
  s += __shfl_xor(s, 32);
  acc.x += __shfl_xor(acc.x, 32);
  acc.y += __shfl_xor(acc.y, 32);
  const float inv = s > 0.f ? 1.f / s : 0.f;
  if (half == 0)
    *reinterpret_cast<float2*>(agg + ((size_t)n << 6) + 2 * l) =
        make_float2(acc.x * inv, acc.y * inv);
}

// ---------------------------------------------------------------------------
// Layer 2 fused: H=1, C=32. Four 16-lane groups process 4 edges at once,
// each lane holds a channel pair. Butterfly merges leave all lanes with the
// full result. Epilogue: bias+relu -> h2, gate scalar inline.
// ---------------------------------------------------------------------------
__launch_bounds__(256) __global__
void gat2_kernel(const __half* __restrict__ xlh, const float* __restrict__ xr,
                 const float* __restrict__ att, const int* __restrict__ row,
                 const int* __restrict__ deg, const int* __restrict__ csr_src,
                 const float* __restrict__ b2, const float* __restrict__ g1w,
                 const float* __restrict__ g1b, const float* __restrict__ g2w,
                 const float* __restrict__ g2b, float* __restrict__ h2,
                 float* __restrict__ gate) {
  const int n =
      __builtin_amdgcn_readfirstlane(blockIdx.x * 4 + (threadIdx.x >> 6));
  if (n >= N_NODES) return;
  const int lane = threadIdx.x & 63;
  const int g = lane >> 4;   // edge group 0..3
  const int m = lane & 15;   // channel-pair index: channels 2m, 2m+1

  const int r0 = __builtin_amdgcn_readfirstlane(row[n]);
  const int dg = __builtin_amdgcn_readfirstlane(deg[n]);

  const float2 xrv =
      *reinterpret_cast<const float2*>(xr + (size_t)n * 32 + 2 * m);
  const float2 attv = *reinterpret_cast<const float2*>(att + 2 * m);

  float s = 0.f;
  float2 acc = make_float2(0.f, 0.f);
  const int Q = (dg + 3) >> 2;  // edge quads

  __half2 xb[2];
#pragma unroll
  for (int k = 0; k < 2; ++k) {
    const int s0 = ld_src(csr_src, r0 + 4 * k + 0, 4 * k + 0, dg);
    const int s1 = ld_src(csr_src, r0 + 4 * k + 1, 4 * k + 1, dg);
    const int s2 = ld_src(csr_src, r0 + 4 * k + 2, 4 * k + 2, dg);
    const int s3 = ld_src(csr_src, r0 + 4 * k + 3, 4 * k + 3, dg);
    const int selLo = (g & 1) ? s1 : s0;
    const int selHi = (g & 1) ? s3 : s2;
    const int sel = (g & 2) ? selHi : selLo;
    xb[k] = *reinterpret_cast<const __half2*>(
        (const char*)xlh + (((size_t)(unsigned)sel) << 6) + 4 * m);
  }
  for (int t = 0; t < Q; t += 2) {
    __half2 xn[2];
#pragma unroll
    for (int k = 0; k < 2; ++k) {
      const int q = t + 2 + k;
      const int s0 = ld_src(csr_src, r0 + 4 * q + 0, 4 * q + 0, dg);
      const int s1 = ld_src(csr_src, r0 + 4 * q + 1, 4 * q + 1, dg);
      const int s2 = ld_src(csr_src, r0 + 4 * q + 2, 4 * q + 2, dg);
      const int s3 = ld_src(csr_src, r0 + 4 * q + 3, 4 * q + 3, dg);
      const int selLo = (g & 1) ? s1 : s0;
      const int selHi = (g & 1) ? s3 : s2;
      const int sel = (g & 2) ? selHi : selLo;
      xn[k] = *reinterpret_cast<const __half2*>(
          (const char*)xlh + (((size_t)(unsigned)sel) << 6) + 4 * m);
    }
#pragma unroll
    for (int k = 0; k < 2; ++k) {
      const float2 a = __half22float2(xb[k]);
      float vx = a.x + xrv.x, vy = a.y + xrv.y;
      vx = fmaxf(vx, 0.2f * vx);
      vy = fmaxf(vy, 0.2f * vy);
      float p = fmaf(vy, attv.y, vx * attv.x);
      p += __shfl_xor(p, 1);
      p += __shfl_xor(p, 2);
      p += __shfl_xor(p, 4);
      p += __shfl_xor(p, 8);  // 16-lane (edge) sum
      float e = __expf(p);
      e = (4 * (t + k) + g < dg) ? e : 0.f;
      s += e;
      acc.x = fmaf(e, a.x, acc.x);
      acc.y = fmaf(e, a.y, acc.y);
    }
#pragma unroll
    for (int k = 0; k < 2; ++k) xb[k] = xn[k];
  }
  // merge the 4 edge groups (butterfly: all lanes get totals)
  s += __shfl_xor(s, 16);
  s += __shfl_xor(s, 32);
  acc.x += __shfl_xor(acc.x, 16);
  acc.x += __shfl_xor(acc.x, 32);
  acc.y += __shfl_xor(acc.y, 16);
  acc.y += __shfl_xor(acc.y, 32);
  const float inv = s > 0.f ? 1.f / s : 0.f;
  const float2 b2v = *reinterpret_cast<const float2*>(b2 + 2 * m);
  const float2 hv2 = make_float2(fmaxf(acc.x * inv + b2v.x, 0.f),
                                 fmaxf(acc.y * inv + b2v.y, 0.f));
  if (g == 0)
    *reinterpret_cast<float2*>(h2 + (size_t)n * 32 + 2 * m) = hv2;

  // redistribute to 1-channel-per-lane layout for the gate matvec
  const int c = lane & 31;
  const float hx = __shfl(hv2.x, c >> 1, 32);
  const float hy = __shfl(hv2.y, c >> 1, 32);
  const float hv = (c & 1) ? hy : hx;
  float sg = g1b[c];
#pragma unroll
  for (int k = 0; k < 32; ++k)
    sg = fmaf(__shfl(hv, k, 32), g1w[k * 32 + c], sg);
  sg = fmaxf(sg, 0.f);
  float pg = sg * g2w[c];
  pg += __shfl_xor(pg, 1);
  pg += __shfl_xor(pg, 2);
  pg += __shfl_xor(pg, 4);
  pg += __shfl_xor(pg, 8);
  pg += __shfl_xor(pg, 16);
  if (lane == 0) gate[n] = pg + g2b[0];
}

// ---------------------------------------------------------------------------
__launch_bounds__(256) __global__
void gepool_kernel(const float* __restrict__ h2, const int* __restrict__ batch,
                   const float* __restrict__ gate, float* __restrict__ gd,
                   float* __restrict__ pooled) {
  __shared__ float pool[G_GRAPHS * 32];
  __shared__ float gdb[G_GRAPHS];
  const int tid = threadIdx.x;
  for (int i = tid; i < G_GRAPHS * 32; i += 256) pool[i] = 0.f;
  if (tid < G_GRAPHS) gdb[tid] = 0.f;
  __syncthreads();
  const int c = tid & 31;
  const int hw = tid >> 5;
  const int start = blockIdx.x * 256;
  const int end = min(N_NODES, start + 256);
  for (int n = start + hw; n < end; n += 8) {
    const int b = batch[n];
    const float ge = __expf(gate[n]);
    atomicAdd(&pool[b * 32 + c], ge * h2[(size_t)n * 32 + c]);
    if (c == 0) atomicAdd(&gdb[b], ge);
  }
  __syncthreads();
  for (int i = tid; i < G_GRAPHS * 32; i += 256)
    if (pool[i] != 0.f) unsafeAtomicAdd(&pooled[i], pool[i]);
  if (tid < G_GRAPHS && gdb[tid] != 0.f) unsafeAtomicAdd(&gd[tid], gdb[tid]);
}

__launch_bounds__(64) __global__
void final_kernel(const float* __restrict__ pooled, const float* __restrict__ gd,
                  const float* __restrict__ l1w, const float* __restrict__ l1b,
                  const float* __restrict__ l2w, const float* __restrict__ l2b,
                  float* __restrict__ out) {
  const int g = blockIdx.x;
  const int lane = threadIdx.x;
  if (lane >= 32) return;
  const float invgd = 1.f / gd[g];
  float s = l1b[lane];
#pragma unroll
  for (int k = 0; k < 32; ++k)
    s = fmaf(pooled[g * 32 + k] * invgd, l1w[k * 32 + lane], s);
  s = fmaxf(s, 0.f);
  float p = s * l2w[lane];
  p += __shfl_xor(p, 1);
  p += __shfl_xor(p, 2);
  p += __shfl_xor(p, 4);
  p += __shfl_xor(p, 8);
  p += __shfl_xor(p, 16);
  if (lane == 0) out[g] = p + l2b[0];
}

// ---------------------------------------------------------------------------
extern "C" void kernel_launch(void* const* d_in, const int* in_sizes, int n_in,
                              void* d_out, int out_size, void* d_ws,
                              size_t ws_size, hipStream_t stream) {
  const float* x    = (const float*)d_in[0];
  const int*   ei   = (const int*)d_in[1];
  const int*   batch= (const int*)d_in[2];
  const float* Wl1  = (const float*)d_in[3];
  const float* Wr1  = (const float*)d_in[4];
  const float* att1 = (const float*)d_in[5];
  const float* b1   = (const float*)d_in[6];
  const float* Wl2  = (const float*)d_in[7];
  const float* Wr2  = (const float*)d_in[8];
  const float* att2 = (const float*)d_in[9];
  const float* b2   = (const float*)d_in[10];
  const float* g1w  = (const float*)d_in[11];
  const float* g1b  = (const float*)d_in[12];
  const float* g2w  = (const float*)d_in[13];
  const float* g2b  = (const float*)d_in[14];
  const float* l1w  = (const float*)d_in[15];
  const float* l1b  = (const float*)d_in[16];
  const float* l2w  = (const float*)d_in[17];
  const float* l2b  = (const float*)d_in[18];
  float* out = (float*)d_out;

  // ---- workspace layout ----
  int* bhist   = (int*)d_ws;            // NBKT (zeroed)
  int* bbase   = bhist + NBKT;          // NBKT
  int* bcursor = bbase + NBKT;          // NBKT
  int* deg     = bcursor + NBKT;        // N (written coalesced by partB)
  int* row     = deg + N_NODES;         // N
  int* csr_src = row + N_NODES;         // E + 16 pad
  int2* staging = (int2*)(csr_src + N_EDGES + 16);  // E int2
  float* fbase = (float*)(staging + N_EDGES);
  float* xr1  = fbase;                         // N*64
  float* agg1 = xr1 + (size_t)N_NODES * 64;    // N*64
  float* gate = agg1 + (size_t)N_NODES * 64;   // N
  float* gd   = gate + N_NODES;                // 64
  float* pooled = gd + G_GRAPHS;               // 64*32
  __half* xl1h = (__half*)(pooled + G_GRAPHS * 32);  // N*64 half
  // layer-2 aliases (stream-ordered producers/consumers)
  __half* xl2h = xl1h;                         // N*32 half
  float* xr2 = xr1;                            // N*32 (first half of xr1)
  float* h2  = xr1 + (size_t)N_NODES * 32;     // N*32 (second half of xr1)

  hipMemsetAsync(bhist, 0, (size_t)NBKT * sizeof(int), stream);
  hipMemsetAsync(gd, 0, (size_t)(G_GRAPHS + G_GRAPHS * 32) * sizeof(float), stream);

  // CSR build: bucket hist -> scan -> partition -> per-bucket deg/row/scatter
  histB_kernel<<<(N_EDGES + 1023) / 1024, 256, 0, stream>>>(ei, bhist);
  bscan_kernel<<<1, 256, 0, stream>>>(bhist, bbase, bcursor);
  partA_kernel<<<(N_EDGES + 4095) / 4096, 1024, 0, stream>>>(ei, bcursor,
                                                             staging);
  partB_kernel<<<NBKT, 256, 0, stream>>>(staging, bbase, bhist, deg, row,
                                         csr_src);

  // Layer 1 (xl staged fp16)
  gemm_dual<128, 64, false, true><<<(N_NODES + 31) / 32, 256, 0, stream>>>(
      x, Wl1, Wr1, nullptr, (void*)xl1h, xr1, N_NODES);
  gat1_kernel<<<(N_NODES + 3) / 4, 256, 0, stream>>>(xl1h, xr1, att1, row, deg,
                                                     csr_src, agg1);

  // Layer 2 (bias1+relu fused into A-load; gate fused into epilogue)
  gemm_dual<64, 32, true, true><<<(N_NODES + 31) / 32, 256, 0, stream>>>(
      agg1, Wl2, Wr2, b1, (void*)xl2h, xr2, N_NODES);
  gat2_kernel<<<(N_NODES + 3) / 4, 256, 0, stream>>>(
      xl2h, xr2, att2, row, deg, csr_src, b2, g1w, g1b, g2w, g2b, h2, gate);

  // Pooling + head (no-max graph softmax)
  gepool_kernel<<<(N_NODES + 255) / 256, 256, 0, stream>>>(h2, batch, gate, gd,
                                                           pooled);
  final_kernel<<<64, 64, 0, stream>>>(pooled, gd, l1w, l1b, l2w, l2b, out);
}